// Round 1
// baseline (8741.608 us; speedup 1.0000x reference)
//
#include <hip/hip_runtime.h>
#include <hip/hip_bf16.h>
#include <math.h>

#define NNODES 50000
#define NEDGES 800000
#define HF 256
#define NEG_SLOPE 0.2f

__device__ __forceinline__ float atomicMaxFloat(float* addr, float v) {
  if (v >= 0.0f)
    return __int_as_float(atomicMax((int*)addr, __float_as_int(v)));
  else
    return __uint_as_float(atomicMin((unsigned int*)addr, __float_as_uint(v)));
}

// ---------------- SGEMM: C[M,256] = act(A[M,256]) @ W[256,256] (+bias) ------
// BM=BN=128, BK=8, 256 threads, 8x8 per thread.
template<bool RELU_IN, bool HAS_BIAS>
__global__ __launch_bounds__(256)
void sgemm_k256(const float* __restrict__ A, const float* __restrict__ W,
                const float* __restrict__ bias, float* __restrict__ C, int M) {
  __shared__ float As[8][128];
  __shared__ float Bs[8][128];
  const int t = threadIdx.x;
  const int brow = blockIdx.x * 128;
  const int bcol = blockIdx.y * 128;
  const int tx = t & 15, ty = t >> 4;

  const int a_row = t >> 1;          // 0..127
  const int a_k   = (t & 1) * 4;     // 0 or 4
  const int b_k   = t >> 5;          // 0..7
  const int b_col = (t & 31) * 4;    // 0..124

  float acc[8][8];
#pragma unroll
  for (int i = 0; i < 8; i++)
#pragma unroll
    for (int j = 0; j < 8; j++) acc[i][j] = 0.f;

  const int gr = brow + a_row;
  const bool a_valid = gr < M;
  const float* Aptr = A + (size_t)(a_valid ? gr : 0) * 256 + a_k;

  for (int k0 = 0; k0 < 256; k0 += 8) {
    float4 av = a_valid ? *(const float4*)(Aptr + k0) : make_float4(0.f, 0.f, 0.f, 0.f);
    if (RELU_IN) {
      av.x = fmaxf(av.x, 0.f); av.y = fmaxf(av.y, 0.f);
      av.z = fmaxf(av.z, 0.f); av.w = fmaxf(av.w, 0.f);
    }
    As[a_k + 0][a_row] = av.x;
    As[a_k + 1][a_row] = av.y;
    As[a_k + 2][a_row] = av.z;
    As[a_k + 3][a_row] = av.w;
    float4 bv = *(const float4*)(W + (size_t)(k0 + b_k) * 256 + bcol + b_col);
    *(float4*)&Bs[b_k][b_col] = bv;
    __syncthreads();
#pragma unroll
    for (int kk = 0; kk < 8; ++kk) {
      float a[8], b[8];
      *(float4*)(a + 0) = *(const float4*)&As[kk][ty * 8 + 0];
      *(float4*)(a + 4) = *(const float4*)&As[kk][ty * 8 + 4];
      *(float4*)(b + 0) = *(const float4*)&Bs[kk][tx * 8 + 0];
      *(float4*)(b + 4) = *(const float4*)&Bs[kk][tx * 8 + 4];
#pragma unroll
      for (int i = 0; i < 8; i++)
#pragma unroll
        for (int j = 0; j < 8; j++) acc[i][j] = fmaf(a[i], b[j], acc[i][j]);
    }
    __syncthreads();
  }

#pragma unroll
  for (int i = 0; i < 8; i++) {
    int r = brow + ty * 8 + i;
    if (r < M) {
      float* cp = C + (size_t)r * 256 + bcol + tx * 8;
#pragma unroll
      for (int jj = 0; jj < 2; jj++) {
        float4 o;
        o.x = acc[i][jj * 4 + 0]; o.y = acc[i][jj * 4 + 1];
        o.z = acc[i][jj * 4 + 2]; o.w = acc[i][jj * 4 + 3];
        if (HAS_BIAS) {
          const float* bp = bias + bcol + tx * 8 + jj * 4;
          o.x += bp[0]; o.y += bp[1]; o.z += bp[2]; o.w += bp[3];
        }
        *(float4*)(cp + jj * 4) = o;
      }
    }
  }
}

// ---------------- el/er row dots -------------------------------------------
__global__ __launch_bounds__(256)
void rowdots(const float* __restrict__ feat, const float* __restrict__ al,
             const float* __restrict__ ar, float* __restrict__ el,
             float* __restrict__ er) {
  int row = blockIdx.x * 4 + (threadIdx.x >> 6);
  int lane = threadIdx.x & 63;
  if (row >= NNODES) return;
  float4 f = *(const float4*)(feat + (size_t)row * HF + lane * 4);
  float4 a = *(const float4*)(al + lane * 4);
  float4 b = *(const float4*)(ar + lane * 4);
  float sl = f.x * a.x + f.y * a.y + f.z * a.z + f.w * a.w;
  float sr = f.x * b.x + f.y * b.y + f.z * b.z + f.w * b.w;
#pragma unroll
  for (int off = 32; off; off >>= 1) {
    sl += __shfl_xor(sl, off);
    sr += __shfl_xor(sr, off);
  }
  if (lane == 0) { el[row] = sl; er[row] = sr; }
}

// ---------------- per-layer init: h=bias, m=-inf, denom=0 ------------------
__global__ void init_layer(float* __restrict__ m, float* __restrict__ denom,
                           float* __restrict__ h, const float* __restrict__ bias) {
  int i = blockIdx.x;
  int j = threadIdx.x;
  h[(size_t)i * HF + j] = bias[j];
  if (j == 0) { m[i] = -INFINITY; denom[i] = 0.f; }
}

// ---------------- edge pass 1: e = leaky_relu(el[s]+er[d]); segmax ---------
__global__ __launch_bounds__(256)
void edge_pass1(const int* __restrict__ src, const int* __restrict__ dst,
                const float* __restrict__ el, const float* __restrict__ er,
                float* __restrict__ ebuf, float* __restrict__ m) {
  int e = blockIdx.x * 256 + threadIdx.x;
  if (e >= NEDGES) return;
  int s = src[e], d = dst[e];
  float x = el[s] + er[d];
  float v = x > 0.f ? x : NEG_SLOPE * x;
  ebuf[e] = v;
  atomicMaxFloat(&m[d], v);
}

// ---------------- edge pass 2: ex = exp(e - m[d]); segsum ------------------
__global__ __launch_bounds__(256)
void edge_pass2(const int* __restrict__ dst, const float* __restrict__ m,
                float* __restrict__ ebuf, float* __restrict__ denom) {
  int e = blockIdx.x * 256 + threadIdx.x;
  if (e >= NEDGES) return;
  int d = dst[e];
  float ex = expf(ebuf[e] - m[d]);
  ebuf[e] = ex;
  unsafeAtomicAdd(&denom[d], ex);
}

// ---------------- edge aggregate: out[d] += (ex/denom[d]) * feat[s] --------
__global__ __launch_bounds__(256)
void edge_agg(const int* __restrict__ src, const int* __restrict__ dst,
              const float* __restrict__ ex, const float* __restrict__ denom,
              const float* __restrict__ feat, float* __restrict__ out) {
  int e = (blockIdx.x * 256 + threadIdx.x) >> 6;
  int lane = threadIdx.x & 63;
  if (e >= NEDGES) return;
  int s = src[e], d = dst[e];
  float a = ex[e] / denom[d];
  float4 f = *(const float4*)(feat + (size_t)s * HF + lane * 4);
  float* o = out + (size_t)d * HF + lane * 4;
  unsafeAtomicAdd(o + 0, f.x * a);
  unsafeAtomicAdd(o + 1, f.y * a);
  unsafeAtomicAdd(o + 2, f.z * a);
  unsafeAtomicAdd(o + 3, f.w * a);
}

// ---------------- readout: sigmoid(concat(h1,h2,h3) @ Wro + bro) -----------
__global__ __launch_bounds__(256)
void readout(const float* __restrict__ h1, const float* __restrict__ h2,
             const float* __restrict__ h3, const float* __restrict__ Wro,
             const float* __restrict__ bro, float* __restrict__ out) {
  int row = blockIdx.x * 4 + (threadIdx.x >> 6);
  int lane = threadIdx.x & 63;
  if (row >= NNODES) return;
  float acc[8];
#pragma unroll
  for (int t2 = 0; t2 < 8; t2++) acc[t2] = 0.f;
  const float* hs0 = h1 + (size_t)row * HF;
  const float* hs1 = h2 + (size_t)row * HF;
  const float* hs2 = h3 + (size_t)row * HF;
#pragma unroll
  for (int part = 0; part < 3; ++part) {
    const float* hp = part == 0 ? hs0 : (part == 1 ? hs1 : hs2);
#pragma unroll
    for (int kk = 0; kk < HF; kk += 64) {
      float x = hp[kk + lane];
      const float* w = Wro + (size_t)(part * HF + kk + lane) * 8;
#pragma unroll
      for (int t2 = 0; t2 < 8; t2++) acc[t2] = fmaf(x, w[t2], acc[t2]);
    }
  }
#pragma unroll
  for (int t2 = 0; t2 < 8; t2++)
#pragma unroll
    for (int off = 32; off; off >>= 1) acc[t2] += __shfl_xor(acc[t2], off);
  if (lane == 0) {
#pragma unroll
    for (int t2 = 0; t2 < 8; t2++) {
      float v = acc[t2] + bro[t2];
      out[(size_t)row * 8 + t2] = 1.f / (1.f + expf(-v));
    }
  }
}

extern "C" void kernel_launch(void* const* d_in, const int* in_sizes, int n_in,
                              void* d_out, int out_size, void* d_ws, size_t ws_size,
                              hipStream_t stream) {
  const float* hv   = (const float*)d_in[0];
  const int*   src  = (const int*)d_in[1];
  const int*   dst  = (const int*)d_in[2];
  const float* W_in = (const float*)d_in[3];
  const float* b_in = (const float*)d_in[4];
  const float* W_ro = (const float*)d_in[5];
  const float* b_ro = (const float*)d_in[6];
  const float* fc[3]   = {(const float*)d_in[7],  (const float*)d_in[11], (const float*)d_in[15]};
  const float* al[3]   = {(const float*)d_in[8],  (const float*)d_in[12], (const float*)d_in[16]};
  const float* ar[3]   = {(const float*)d_in[9],  (const float*)d_in[13], (const float*)d_in[17]};
  const float* bias[3] = {(const float*)d_in[10], (const float*)d_in[14], (const float*)d_in[18]};
  float* out = (float*)d_out;

  const size_t NH = (size_t)NNODES * HF;
  float* ws = (float*)d_ws;
  float* h1   = ws;
  float* h2   = ws + NH;
  float* h3   = ws + 2 * NH;        // also used as h0 (dead before layer 3 writes)
  float* feat = ws + 3 * NH;
  float* el   = ws + 4 * NH;
  float* er   = el + NNODES;
  float* m    = er + NNODES;
  float* denom= m + NNODES;
  float* ebuf = denom + NNODES;
  float* h0 = h3;

  const dim3 gemm_grid((NNODES + 127) / 128, 2);
  const int rd_grid = (NNODES + 3) / 4;
  const int ep_grid = (NEDGES + 255) / 256;
  const int agg_grid = NEDGES / 4;  // one wave per edge, 4 waves/block

  // h0 = hv @ W_in + b_in
  sgemm_k256<false, true><<<gemm_grid, 256, 0, stream>>>(hv, W_in, b_in, h0, NNODES);

  float* hprev = h0;
  float* houts[3] = {h1, h2, h3};
  for (int l = 0; l < 3; ++l) {
    float* hl = houts[l];
    // feat = relu(hprev) @ fc_l
    sgemm_k256<true, false><<<gemm_grid, 256, 0, stream>>>(hprev, fc[l], nullptr, feat, NNODES);
    rowdots<<<rd_grid, 256, 0, stream>>>(feat, al[l], ar[l], el, er);
    init_layer<<<NNODES, 256, 0, stream>>>(m, denom, hl, bias[l]);
    edge_pass1<<<ep_grid, 256, 0, stream>>>(src, dst, el, er, ebuf, m);
    edge_pass2<<<ep_grid, 256, 0, stream>>>(dst, m, ebuf, denom);
    edge_agg<<<agg_grid, 256, 0, stream>>>(src, dst, ebuf, denom, feat, hl);
    hprev = hl;
  }

  readout<<<rd_grid, 256, 0, stream>>>(h1, h2, h3, W_ro, b_ro, out);
}

// Round 2
// 1051.077 us; speedup vs baseline: 8.3168x; 8.3168x over previous
//
#include <hip/hip_runtime.h>
#include <hip/hip_bf16.h>
#include <math.h>

#define NNODES 50000
#define NEDGES 800000
#define HF 256
#define NEG_SLOPE 0.2f

// ---------------- SGEMM: C[M,256] = act(A[M,256]) @ W[256,256] (+bias) ------
// BM=BN=128, BK=8, 256 threads, 8x8 per thread.
template<bool RELU_IN, bool HAS_BIAS>
__global__ __launch_bounds__(256)
void sgemm_k256(const float* __restrict__ A, const float* __restrict__ W,
                const float* __restrict__ bias, float* __restrict__ C, int M) {
  __shared__ float As[8][128];
  __shared__ float Bs[8][128];
  const int t = threadIdx.x;
  const int brow = blockIdx.x * 128;
  const int bcol = blockIdx.y * 128;
  const int tx = t & 15, ty = t >> 4;

  const int a_row = t >> 1;          // 0..127
  const int a_k   = (t & 1) * 4;     // 0 or 4
  const int b_k   = t >> 5;          // 0..7
  const int b_col = (t & 31) * 4;    // 0..124

  float acc[8][8];
#pragma unroll
  for (int i = 0; i < 8; i++)
#pragma unroll
    for (int j = 0; j < 8; j++) acc[i][j] = 0.f;

  const int gr = brow + a_row;
  const bool a_valid = gr < M;
  const float* Aptr = A + (size_t)(a_valid ? gr : 0) * 256 + a_k;

  for (int k0 = 0; k0 < 256; k0 += 8) {
    float4 av = a_valid ? *(const float4*)(Aptr + k0) : make_float4(0.f, 0.f, 0.f, 0.f);
    if (RELU_IN) {
      av.x = fmaxf(av.x, 0.f); av.y = fmaxf(av.y, 0.f);
      av.z = fmaxf(av.z, 0.f); av.w = fmaxf(av.w, 0.f);
    }
    As[a_k + 0][a_row] = av.x;
    As[a_k + 1][a_row] = av.y;
    As[a_k + 2][a_row] = av.z;
    As[a_k + 3][a_row] = av.w;
    float4 bv = *(const float4*)(W + (size_t)(k0 + b_k) * 256 + bcol + b_col);
    *(float4*)&Bs[b_k][b_col] = bv;
    __syncthreads();
#pragma unroll
    for (int kk = 0; kk < 8; ++kk) {
      float a[8], b[8];
      *(float4*)(a + 0) = *(const float4*)&As[kk][ty * 8 + 0];
      *(float4*)(a + 4) = *(const float4*)&As[kk][ty * 8 + 4];
      *(float4*)(b + 0) = *(const float4*)&Bs[kk][tx * 8 + 0];
      *(float4*)(b + 4) = *(const float4*)&Bs[kk][tx * 8 + 4];
#pragma unroll
      for (int i = 0; i < 8; i++)
#pragma unroll
        for (int j = 0; j < 8; j++) acc[i][j] = fmaf(a[i], b[j], acc[i][j]);
    }
    __syncthreads();
  }

#pragma unroll
  for (int i = 0; i < 8; i++) {
    int r = brow + ty * 8 + i;
    if (r < M) {
      float* cp = C + (size_t)r * 256 + bcol + tx * 8;
#pragma unroll
      for (int jj = 0; jj < 2; jj++) {
        float4 o;
        o.x = acc[i][jj * 4 + 0]; o.y = acc[i][jj * 4 + 1];
        o.z = acc[i][jj * 4 + 2]; o.w = acc[i][jj * 4 + 3];
        if (HAS_BIAS) {
          const float* bp = bias + bcol + tx * 8 + jj * 4;
          o.x += bp[0]; o.y += bp[1]; o.z += bp[2]; o.w += bp[3];
        }
        *(float4*)(cp + jj * 4) = o;
      }
    }
  }
}

// ---------------- el/er row dots -------------------------------------------
__global__ __launch_bounds__(256)
void rowdots(const float* __restrict__ feat, const float* __restrict__ al,
             const float* __restrict__ ar, float* __restrict__ el,
             float* __restrict__ er) {
  int row = blockIdx.x * 4 + (threadIdx.x >> 6);
  int lane = threadIdx.x & 63;
  if (row >= NNODES) return;
  float4 f = *(const float4*)(feat + (size_t)row * HF + lane * 4);
  float4 a = *(const float4*)(al + lane * 4);
  float4 b = *(const float4*)(ar + lane * 4);
  float sl = f.x * a.x + f.y * a.y + f.z * a.z + f.w * a.w;
  float sr = f.x * b.x + f.y * b.y + f.z * b.z + f.w * b.w;
#pragma unroll
  for (int off = 32; off; off >>= 1) {
    sl += __shfl_xor(sl, off);
    sr += __shfl_xor(sr, off);
  }
  if (lane == 0) { el[row] = sl; er[row] = sr; }
}

// ---------------- CSR build -------------------------------------------------
__global__ __launch_bounds__(256)
void hist_dst(const int* __restrict__ dst, int* __restrict__ cnt) {
  int e = blockIdx.x * 256 + threadIdx.x;
  if (e < NEDGES) atomicAdd(&cnt[dst[e]], 1);
}

// single block, 1024 threads: exclusive scan of cnt -> rowptr (and woff copy)
__global__ __launch_bounds__(1024)
void scan_rowptr(const int* __restrict__ cnt, int* __restrict__ rowptr,
                 int* __restrict__ woff) {
  __shared__ int partial[1024];
  const int t = threadIdx.x;
  const int CH = 49;  // 1024*49 = 50176 >= 50000
  const int base = t * CH;
  int s = 0;
  for (int i = 0; i < CH; i++) {
    int idx = base + i;
    if (idx < NNODES) s += cnt[idx];
  }
  partial[t] = s;
  __syncthreads();
  for (int off = 1; off < 1024; off <<= 1) {
    int v = (t >= off) ? partial[t - off] : 0;
    __syncthreads();
    partial[t] += v;
    __syncthreads();
  }
  int run = (t > 0) ? partial[t - 1] : 0;
  for (int i = 0; i < CH; i++) {
    int idx = base + i;
    if (idx < NNODES) {
      rowptr[idx] = run;
      woff[idx] = run;
      run += cnt[idx];
    }
  }
  if (t == 1023) rowptr[NNODES] = partial[1023];
}

__global__ __launch_bounds__(256)
void scatter_csr(const int* __restrict__ src, const int* __restrict__ dst,
                 int* __restrict__ woff, int* __restrict__ col) {
  int e = blockIdx.x * 256 + threadIdx.x;
  if (e >= NEDGES) return;
  int d = dst[e];
  int p = atomicAdd(&woff[d], 1);
  col[p] = src[e];
}

// ---------------- fused GAT edge phase over CSR: one wave per dst ----------
// h[d] = bias + (sum_e exp(lrelu(el[s]+er[d]) - m) * feat[s]) / denom
__global__ __launch_bounds__(256)
void gat_csr(const int* __restrict__ rowptr, const int* __restrict__ col,
             const float* __restrict__ el, const float* __restrict__ er,
             const float* __restrict__ feat, const float* __restrict__ bias,
             float* __restrict__ h) {
  int d = blockIdx.x * 4 + (threadIdx.x >> 6);
  int lane = threadIdx.x & 63;
  if (d >= NNODES) return;
  const int start = rowptr[d], end = rowptr[d + 1];
  float4 b4 = *(const float4*)(bias + lane * 4);
  float* hp = h + (size_t)d * HF + lane * 4;
  if (start == end) { *(float4*)hp = b4; return; }
  const float erd = er[d];

  // pass A: wave max over in-edges (lane-parallel)
  float mx = -INFINITY;
  for (int j = start + lane; j < end; j += 64) {
    float x = el[col[j]] + erd;
    x = x > 0.f ? x : NEG_SLOPE * x;
    mx = fmaxf(mx, x);
  }
#pragma unroll
  for (int off = 32; off; off >>= 1) mx = fmaxf(mx, __shfl_xor(mx, off));

  // pass B: denom (lane-parallel)
  float sm = 0.f;
  for (int j = start + lane; j < end; j += 64) {
    float x = el[col[j]] + erd;
    x = x > 0.f ? x : NEG_SLOPE * x;
    sm += __expf(x - mx);
  }
#pragma unroll
  for (int off = 32; off; off >>= 1) sm += __shfl_xor(sm, off);

  // pass C: whole wave per edge, accumulate ex * feat[s]
  float4 acc = make_float4(0.f, 0.f, 0.f, 0.f);
  for (int j = start; j < end; ++j) {
    int s = col[j];                 // wave-uniform broadcast load
    float x = el[s] + erd;
    x = x > 0.f ? x : NEG_SLOPE * x;
    float ex = __expf(x - mx);
    float4 f = *(const float4*)(feat + (size_t)s * HF + lane * 4);
    acc.x = fmaf(ex, f.x, acc.x);
    acc.y = fmaf(ex, f.y, acc.y);
    acc.z = fmaf(ex, f.z, acc.z);
    acc.w = fmaf(ex, f.w, acc.w);
  }
  const float rcp = 1.f / sm;
  float4 o;
  o.x = fmaf(acc.x, rcp, b4.x);
  o.y = fmaf(acc.y, rcp, b4.y);
  o.z = fmaf(acc.z, rcp, b4.z);
  o.w = fmaf(acc.w, rcp, b4.w);
  *(float4*)hp = o;
}

// ---------------- readout: sigmoid(concat(h1,h2,h3) @ Wro + bro) -----------
__global__ __launch_bounds__(256)
void readout(const float* __restrict__ h1, const float* __restrict__ h2,
             const float* __restrict__ h3, const float* __restrict__ Wro,
             const float* __restrict__ bro, float* __restrict__ out) {
  int row = blockIdx.x * 4 + (threadIdx.x >> 6);
  int lane = threadIdx.x & 63;
  if (row >= NNODES) return;
  float acc[8];
#pragma unroll
  for (int t2 = 0; t2 < 8; t2++) acc[t2] = 0.f;
  const float* hs0 = h1 + (size_t)row * HF;
  const float* hs1 = h2 + (size_t)row * HF;
  const float* hs2 = h3 + (size_t)row * HF;
#pragma unroll
  for (int part = 0; part < 3; ++part) {
    const float* hp = part == 0 ? hs0 : (part == 1 ? hs1 : hs2);
#pragma unroll
    for (int kk = 0; kk < HF; kk += 64) {
      float x = hp[kk + lane];
      const float* w = Wro + (size_t)(part * HF + kk + lane) * 8;
#pragma unroll
      for (int t2 = 0; t2 < 8; t2++) acc[t2] = fmaf(x, w[t2], acc[t2]);
    }
  }
#pragma unroll
  for (int t2 = 0; t2 < 8; t2++)
#pragma unroll
    for (int off = 32; off; off >>= 1) acc[t2] += __shfl_xor(acc[t2], off);
  if (lane == 0) {
#pragma unroll
    for (int t2 = 0; t2 < 8; t2++) {
      float v = acc[t2] + bro[t2];
      out[(size_t)row * 8 + t2] = 1.f / (1.f + expf(-v));
    }
  }
}

extern "C" void kernel_launch(void* const* d_in, const int* in_sizes, int n_in,
                              void* d_out, int out_size, void* d_ws, size_t ws_size,
                              hipStream_t stream) {
  const float* hv   = (const float*)d_in[0];
  const int*   src  = (const int*)d_in[1];
  const int*   dst  = (const int*)d_in[2];
  const float* W_in = (const float*)d_in[3];
  const float* b_in = (const float*)d_in[4];
  const float* W_ro = (const float*)d_in[5];
  const float* b_ro = (const float*)d_in[6];
  const float* fc[3]   = {(const float*)d_in[7],  (const float*)d_in[11], (const float*)d_in[15]};
  const float* al[3]   = {(const float*)d_in[8],  (const float*)d_in[12], (const float*)d_in[16]};
  const float* ar[3]   = {(const float*)d_in[9],  (const float*)d_in[13], (const float*)d_in[17]};
  const float* bias[3] = {(const float*)d_in[10], (const float*)d_in[14], (const float*)d_in[18]};
  float* out = (float*)d_out;

  const size_t NH = (size_t)NNODES * HF;
  float* ws = (float*)d_ws;
  float* h1   = ws;
  float* h2   = ws + NH;
  float* h3   = ws + 2 * NH;        // also used as h0 (dead before layer 3 writes)
  float* feat = ws + 3 * NH;
  float* el   = ws + 4 * NH;
  float* er   = el + NNODES;
  int* rowptr = (int*)(er + NNODES);          // NNODES+1
  int* woff   = rowptr + NNODES + 1;          // NNODES
  int* cnt    = woff + NNODES;                // NNODES
  int* col    = cnt + NNODES;                 // NEDGES
  float* h0 = h3;

  const dim3 gemm_grid((NNODES + 127) / 128, 2);
  const int rd_grid = (NNODES + 3) / 4;
  const int ep_grid = (NEDGES + 255) / 256;
  const int gat_grid = (NNODES + 3) / 4;

  // ---- build CSR (dst-sorted adjacency), reused by all 3 layers ----
  hipMemsetAsync(cnt, 0, NNODES * sizeof(int), stream);
  hist_dst<<<ep_grid, 256, 0, stream>>>(dst, cnt);
  scan_rowptr<<<1, 1024, 0, stream>>>(cnt, rowptr, woff);
  scatter_csr<<<ep_grid, 256, 0, stream>>>(src, dst, woff, col);

  // h0 = hv @ W_in + b_in
  sgemm_k256<false, true><<<gemm_grid, 256, 0, stream>>>(hv, W_in, b_in, h0, NNODES);

  float* hprev = h0;
  float* houts[3] = {h1, h2, h3};
  for (int l = 0; l < 3; ++l) {
    float* hl = houts[l];
    // feat = relu(hprev) @ fc_l
    sgemm_k256<true, false><<<gemm_grid, 256, 0, stream>>>(hprev, fc[l], nullptr, feat, NNODES);
    rowdots<<<rd_grid, 256, 0, stream>>>(feat, al[l], ar[l], el, er);
    gat_csr<<<gat_grid, 256, 0, stream>>>(rowptr, col, el, er, feat, bias[l], hl);
    hprev = hl;
  }

  readout<<<rd_grid, 256, 0, stream>>>(h1, h2, h3, W_ro, b_ro, out);
}

// Round 3
// 700.321 us; speedup vs baseline: 12.4823x; 1.5009x over previous
//
#include <hip/hip_runtime.h>
#include <hip/hip_bf16.h>
#include <math.h>

#define NNODES 50000
#define NEDGES 800000
#define HF 256
#define NEG_SLOPE 0.2f
#define NB 196  // ceil(NNODES/256)

typedef short bf16x8 __attribute__((ext_vector_type(8)));
typedef float f32x4 __attribute__((ext_vector_type(4)));

__device__ __forceinline__ unsigned short f2bf(float f) {
  unsigned u = __float_as_uint(f);
  unsigned r = u + 0x7FFFu + ((u >> 16) & 1u);
  return (unsigned short)(r >> 16);
}

// ---------------- W^T bf16 pre-convert: WT[mat][n][k] = bf16(W[mat][k][n]) --
__global__ __launch_bounds__(256)
void conv_wt(const float* __restrict__ W0, const float* __restrict__ W1,
             const float* __restrict__ W2, const float* __restrict__ W3,
             unsigned short* __restrict__ WT) {
  int mat = blockIdx.y;
  const float* W = mat == 0 ? W0 : (mat == 1 ? W1 : (mat == 2 ? W2 : W3));
  int i = blockIdx.x * 256 + threadIdx.x;   // output-linear: coalesced writes
  int n = i >> 8, k = i & 255;
  WT[(size_t)mat * 65536 + i] = f2bf(W[(size_t)k * 256 + n]);
}

// ---------------- bf16 MFMA GEMM: C[M,256] = act(A) @ W (+bias) ------------
// 256 thr = 4 waves (2x2), tile 128x128, BK=32, mfma_f32_16x16x32_bf16.
template<bool RELU_IN, bool HAS_BIAS>
__global__ __launch_bounds__(256)
void gemm_bf16(const float* __restrict__ A, const unsigned short* __restrict__ WT,
               const float* __restrict__ bias, float* __restrict__ C, int M) {
  __shared__ unsigned short As[128 * 32];
  __shared__ unsigned short Bs[128 * 32];
  const int t = threadIdx.x;
  const int lane = t & 63;
  const int w = t >> 6;
  const int wr = (w >> 1) * 64;
  const int wc = (w & 1) * 64;
  const int brow = blockIdx.x * 128;
  const int bcol = blockIdx.y * 128;

  f32x4 acc[4][4];
#pragma unroll
  for (int i = 0; i < 4; i++)
#pragma unroll
    for (int j = 0; j < 4; j++) acc[i][j] = (f32x4)(0.f);

  // staging: thread t covers row ar (both tiles), 16 k-values at offset ak
  const int ar = t >> 1;
  const int ak = (t & 1) * 16;
  const int grow = brow + ar;
  const bool avalid = grow < M;
  const float* Ap = A + (size_t)(avalid ? grow : 0) * 256 + ak;
  const unsigned short* Bp = WT + (size_t)(bcol + ar) * 256 + ak;

  // swizzled LDS byte offsets: addr = row*64 + kbyte, XOR ((row&7)<<4)
  const int aw0 = ((ar * 64 + ak * 2) ^ ((ar & 7) << 4));
  const int aw1 = ((ar * 64 + ak * 2 + 16) ^ ((ar & 7) << 4));

  // fragment read offsets (fixed per-lane; tile holds k-local 0..31)
  const int fr = lane & 15, fq = lane >> 4;
  int ard[4], brd[4];
#pragma unroll
  for (int i = 0; i < 4; i++) {
    int rowA = wr + i * 16 + fr;
    ard[i] = ((rowA * 64 + fq * 16) ^ ((rowA & 7) << 4));
    int rowB = wc + i * 16 + fr;
    brd[i] = ((rowB * 64 + fq * 16) ^ ((rowB & 7) << 4));
  }

  for (int k0 = 0; k0 < 256; k0 += 32) {
    // stage A (fp32 -> bf16, relu fused)
    union { unsigned short u[8]; uint4 v; } p0, p1;
    {
      float fv[16];
      float4 x0 = avalid ? *(const float4*)(Ap + k0 + 0)  : make_float4(0,0,0,0);
      float4 x1 = avalid ? *(const float4*)(Ap + k0 + 4)  : make_float4(0,0,0,0);
      float4 x2 = avalid ? *(const float4*)(Ap + k0 + 8)  : make_float4(0,0,0,0);
      float4 x3 = avalid ? *(const float4*)(Ap + k0 + 12) : make_float4(0,0,0,0);
      fv[0]=x0.x; fv[1]=x0.y; fv[2]=x0.z; fv[3]=x0.w;
      fv[4]=x1.x; fv[5]=x1.y; fv[6]=x1.z; fv[7]=x1.w;
      fv[8]=x2.x; fv[9]=x2.y; fv[10]=x2.z; fv[11]=x2.w;
      fv[12]=x3.x; fv[13]=x3.y; fv[14]=x3.z; fv[15]=x3.w;
#pragma unroll
      for (int e = 0; e < 8; e++) {
        float a = fv[e], b = fv[8 + e];
        if (RELU_IN) { a = fmaxf(a, 0.f); b = fmaxf(b, 0.f); }
        p0.u[e] = f2bf(a); p1.u[e] = f2bf(b);
      }
      *(uint4*)((char*)As + aw0) = p0.v;
      *(uint4*)((char*)As + aw1) = p1.v;
    }
    // stage B (already bf16, n-major)
    {
      uint4 b0 = *(const uint4*)(Bp + k0);
      uint4 b1 = *(const uint4*)(Bp + k0 + 8);
      *(uint4*)((char*)Bs + aw0) = b0;
      *(uint4*)((char*)Bs + aw1) = b1;
    }
    __syncthreads();
    bf16x8 af[4], bfr[4];
#pragma unroll
    for (int i = 0; i < 4; i++) {
      af[i]  = *(const bf16x8*)((const char*)As + ard[i]);
      bfr[i] = *(const bf16x8*)((const char*)Bs + brd[i]);
    }
#pragma unroll
    for (int i = 0; i < 4; i++)
#pragma unroll
      for (int j = 0; j < 4; j++)
        acc[i][j] = __builtin_amdgcn_mfma_f32_16x16x32_bf16(af[i], bfr[j], acc[i][j], 0, 0, 0);
    __syncthreads();
  }

  // epilogue: D row = (lane>>4)*4 + reg, col = lane&15  [verified layout]
#pragma unroll
  for (int j = 0; j < 4; j++) {
    const int col = bcol + wc + j * 16 + fr;
    const float bj = HAS_BIAS ? bias[col] : 0.f;
#pragma unroll
    for (int i = 0; i < 4; i++) {
#pragma unroll
      for (int r = 0; r < 4; r++) {
        int row = brow + wr + i * 16 + fq * 4 + r;
        if (row < M) C[(size_t)row * 256 + col] = acc[i][j][r] + bj;
      }
    }
  }
}

// ---------------- el/er row dots -------------------------------------------
__global__ __launch_bounds__(256)
void rowdots(const float* __restrict__ feat, const float* __restrict__ al,
             const float* __restrict__ ar, float* __restrict__ el,
             float* __restrict__ er) {
  int row = blockIdx.x * 4 + (threadIdx.x >> 6);
  int lane = threadIdx.x & 63;
  if (row >= NNODES) return;
  float4 f = *(const float4*)(feat + (size_t)row * HF + lane * 4);
  float4 a = *(const float4*)(al + lane * 4);
  float4 b = *(const float4*)(ar + lane * 4);
  float sl = f.x * a.x + f.y * a.y + f.z * a.z + f.w * a.w;
  float sr = f.x * b.x + f.y * b.y + f.z * b.z + f.w * b.w;
#pragma unroll
  for (int off = 32; off; off >>= 1) {
    sl += __shfl_xor(sl, off);
    sr += __shfl_xor(sr, off);
  }
  if (lane == 0) { el[row] = sl; er[row] = sr; }
}

// ---------------- CSR build -------------------------------------------------
__global__ __launch_bounds__(256)
void hist_dst(const int* __restrict__ dst, int* __restrict__ cnt) {
  int e = blockIdx.x * 256 + threadIdx.x;
  if (e < NEDGES) atomicAdd(&cnt[dst[e]], 1);
}

__global__ __launch_bounds__(256)
void block_sums(const int* __restrict__ cnt, int* __restrict__ bsum) {
  __shared__ int sm[256];
  int t = threadIdx.x;
  int i = blockIdx.x * 256 + t;
  sm[t] = (i < NNODES) ? cnt[i] : 0;
  __syncthreads();
  for (int off = 128; off; off >>= 1) {
    if (t < off) sm[t] += sm[t + off];
    __syncthreads();
  }
  if (t == 0) bsum[blockIdx.x] = sm[0];
}

__global__ __launch_bounds__(256)
void scan_bsums(const int* __restrict__ bsum, int* __restrict__ boff) {
  __shared__ int sm[256];
  int t = threadIdx.x;
  sm[t] = (t < NB) ? bsum[t] : 0;
  __syncthreads();
  for (int off = 1; off < 256; off <<= 1) {
    int v = (t >= off) ? sm[t - off] : 0;
    __syncthreads();
    sm[t] += v;
    __syncthreads();
  }
  if (t < NB) boff[t] = (t == 0) ? 0 : sm[t - 1];
}

__global__ __launch_bounds__(256)
void write_rowptr(const int* __restrict__ cnt, const int* __restrict__ boff,
                  int* __restrict__ rowptr, int* __restrict__ woff) {
  __shared__ int sm[256];
  int t = threadIdx.x;
  int i = blockIdx.x * 256 + t;
  int v = (i < NNODES) ? cnt[i] : 0;
  sm[t] = v;
  __syncthreads();
  for (int off = 1; off < 256; off <<= 1) {
    int x = (t >= off) ? sm[t - off] : 0;
    __syncthreads();
    sm[t] += x;
    __syncthreads();
  }
  int excl = boff[blockIdx.x] + sm[t] - v;
  if (i < NNODES) { rowptr[i] = excl; woff[i] = excl; }
  if (i == NNODES - 1) rowptr[NNODES] = excl + v;
}

__global__ __launch_bounds__(256)
void scatter_csr(const int* __restrict__ src, const int* __restrict__ dst,
                 int* __restrict__ woff, int* __restrict__ col) {
  int e = blockIdx.x * 256 + threadIdx.x;
  if (e >= NEDGES) return;
  int d = dst[e];
  int p = atomicAdd(&woff[d], 1);
  col[p] = src[e];
}

// ---------------- fused GAT edge phase over CSR: one wave per dst ----------
__global__ __launch_bounds__(256)
void gat_csr(const int* __restrict__ rowptr, const int* __restrict__ col,
             const float* __restrict__ el, const float* __restrict__ er,
             const float* __restrict__ feat, const float* __restrict__ bias,
             float* __restrict__ h) {
  int d = blockIdx.x * 4 + (threadIdx.x >> 6);
  int lane = threadIdx.x & 63;
  if (d >= NNODES) return;
  const int start = rowptr[d], end = rowptr[d + 1];
  float4 b4 = *(const float4*)(bias + lane * 4);
  float* hp = h + (size_t)d * HF + lane * 4;
  if (start == end) { *(float4*)hp = b4; return; }
  const float erd = er[d];

  float mx = -INFINITY;
  for (int j = start + lane; j < end; j += 64) {
    float x = el[col[j]] + erd;
    x = x > 0.f ? x : NEG_SLOPE * x;
    mx = fmaxf(mx, x);
  }
#pragma unroll
  for (int off = 32; off; off >>= 1) mx = fmaxf(mx, __shfl_xor(mx, off));

  float sm = 0.f;
  for (int j = start + lane; j < end; j += 64) {
    float x = el[col[j]] + erd;
    x = x > 0.f ? x : NEG_SLOPE * x;
    sm += __expf(x - mx);
  }
#pragma unroll
  for (int off = 32; off; off >>= 1) sm += __shfl_xor(sm, off);

  float4 acc = make_float4(0.f, 0.f, 0.f, 0.f);
  for (int j = start; j < end; ++j) {
    int s = col[j];
    float x = el[s] + erd;
    x = x > 0.f ? x : NEG_SLOPE * x;
    float ex = __expf(x - mx);
    float4 f = *(const float4*)(feat + (size_t)s * HF + lane * 4);
    acc.x = fmaf(ex, f.x, acc.x);
    acc.y = fmaf(ex, f.y, acc.y);
    acc.z = fmaf(ex, f.z, acc.z);
    acc.w = fmaf(ex, f.w, acc.w);
  }
  const float rcp = 1.f / sm;
  float4 o;
  o.x = fmaf(acc.x, rcp, b4.x);
  o.y = fmaf(acc.y, rcp, b4.y);
  o.z = fmaf(acc.z, rcp, b4.z);
  o.w = fmaf(acc.w, rcp, b4.w);
  *(float4*)hp = o;
}

// ---------------- readout: sigmoid(concat(h1,h2,h3) @ Wro + bro) -----------
__global__ __launch_bounds__(256)
void readout(const float* __restrict__ h1, const float* __restrict__ h2,
             const float* __restrict__ h3, const float* __restrict__ Wro,
             const float* __restrict__ bro, float* __restrict__ out) {
  int row = blockIdx.x * 4 + (threadIdx.x >> 6);
  int lane = threadIdx.x & 63;
  if (row >= NNODES) return;
  float acc[8];
#pragma unroll
  for (int t2 = 0; t2 < 8; t2++) acc[t2] = 0.f;
  const float* hs0 = h1 + (size_t)row * HF;
  const float* hs1 = h2 + (size_t)row * HF;
  const float* hs2 = h3 + (size_t)row * HF;
#pragma unroll
  for (int part = 0; part < 3; ++part) {
    const float* hp = part == 0 ? hs0 : (part == 1 ? hs1 : hs2);
#pragma unroll
    for (int kk = 0; kk < HF; kk += 64) {
      float x = hp[kk + lane];
      const float* w = Wro + (size_t)(part * HF + kk + lane) * 8;
#pragma unroll
      for (int t2 = 0; t2 < 8; t2++) acc[t2] = fmaf(x, w[t2], acc[t2]);
    }
  }
#pragma unroll
  for (int t2 = 0; t2 < 8; t2++)
#pragma unroll
    for (int off = 32; off; off >>= 1) acc[t2] += __shfl_xor(acc[t2], off);
  if (lane == 0) {
#pragma unroll
    for (int t2 = 0; t2 < 8; t2++) {
      float v = acc[t2] + bro[t2];
      out[(size_t)row * 8 + t2] = 1.f / (1.f + expf(-v));
    }
  }
}

extern "C" void kernel_launch(void* const* d_in, const int* in_sizes, int n_in,
                              void* d_out, int out_size, void* d_ws, size_t ws_size,
                              hipStream_t stream) {
  const float* hv   = (const float*)d_in[0];
  const int*   src  = (const int*)d_in[1];
  const int*   dst  = (const int*)d_in[2];
  const float* W_in = (const float*)d_in[3];
  const float* b_in = (const float*)d_in[4];
  const float* W_ro = (const float*)d_in[5];
  const float* b_ro = (const float*)d_in[6];
  const float* fc[3]   = {(const float*)d_in[7],  (const float*)d_in[11], (const float*)d_in[15]};
  const float* al[3]   = {(const float*)d_in[8],  (const float*)d_in[12], (const float*)d_in[16]};
  const float* ar[3]   = {(const float*)d_in[9],  (const float*)d_in[13], (const float*)d_in[17]};
  const float* bias[3] = {(const float*)d_in[10], (const float*)d_in[14], (const float*)d_in[18]};
  float* out = (float*)d_out;

  const size_t NH = (size_t)NNODES * HF;
  float* ws = (float*)d_ws;
  float* h1   = ws;
  float* h2   = ws + NH;
  float* h3   = ws + 2 * NH;        // also used as h0 (dead before layer 3 writes)
  float* feat = ws + 3 * NH;
  float* el   = ws + 4 * NH;
  float* er   = el + NNODES;
  int* rowptr = (int*)(er + NNODES);          // NNODES+1
  int* woff   = rowptr + NNODES + 1;          // NNODES
  int* cnt    = woff + NNODES;                // NNODES
  int* bsum   = cnt + NNODES;                 // 256
  int* boff   = bsum + 256;                   // 256
  int* col    = boff + 256;                   // NEDGES
  unsigned short* WT = (unsigned short*)(col + NEDGES);  // 4*65536 bf16
  float* h0 = h3;

  const dim3 gemm_grid((NNODES + 127) / 128, 2);
  const int rd_grid = (NNODES + 3) / 4;
  const int ep_grid = (NEDGES + 255) / 256;
  const int gat_grid = (NNODES + 3) / 4;

  // ---- weights -> bf16 W^T (once per launch) ----
  conv_wt<<<dim3(256, 4), 256, 0, stream>>>(W_in, fc[0], fc[1], fc[2], WT);

  // ---- build CSR (dst-sorted adjacency), reused by all 3 layers ----
  hipMemsetAsync(cnt, 0, NNODES * sizeof(int), stream);
  hist_dst<<<ep_grid, 256, 0, stream>>>(dst, cnt);
  block_sums<<<NB, 256, 0, stream>>>(cnt, bsum);
  scan_bsums<<<1, 256, 0, stream>>>(bsum, boff);
  write_rowptr<<<NB, 256, 0, stream>>>(cnt, boff, rowptr, woff);
  scatter_csr<<<ep_grid, 256, 0, stream>>>(src, dst, woff, col);

  // h0 = hv @ W_in + b_in
  gemm_bf16<false, true><<<gemm_grid, 256, 0, stream>>>(hv, WT, b_in, h0, NNODES);

  float* hprev = h0;
  float* houts[3] = {h1, h2, h3};
  for (int l = 0; l < 3; ++l) {
    float* hl = houts[l];
    // feat = relu(hprev) @ fc_l
    gemm_bf16<true, false><<<gemm_grid, 256, 0, stream>>>(
        hprev, WT + (size_t)(l + 1) * 65536, nullptr, feat, NNODES);
    rowdots<<<rd_grid, 256, 0, stream>>>(feat, al[l], ar[l], el, er);
    gat_csr<<<gat_grid, 256, 0, stream>>>(rowptr, col, el, er, feat, bias[l], hl);
    hprev = hl;
  }

  readout<<<rd_grid, 256, 0, stream>>>(h1, h2, h3, W_ro, b_ro, out);
}

// Round 4
// 490.399 us; speedup vs baseline: 17.8255x; 1.4281x over previous
//
#include <hip/hip_runtime.h>
#include <hip/hip_bf16.h>
#include <math.h>

#define NNODES 50000
#define NEDGES 800000
#define HF 256
#define NEG_SLOPE 0.2f
#define NB 196  // ceil(NNODES/256)

typedef short bf16x8 __attribute__((ext_vector_type(8)));
typedef float f32x4 __attribute__((ext_vector_type(4)));

__device__ __forceinline__ unsigned short f2bf(float f) {
  unsigned u = __float_as_uint(f);
  unsigned r = u + 0x7FFFu + ((u >> 16) & 1u);
  return (unsigned short)(r >> 16);
}
__device__ __forceinline__ float bf2f(unsigned short u) {
  return __uint_as_float((unsigned)u << 16);
}
__device__ __forceinline__ unsigned relu_bf2(unsigned v) {
  unsigned lo = v & 0x0000FFFFu;
  unsigned hi = v & 0xFFFF0000u;
  if (v & 0x00008000u) lo = 0u;
  if (v & 0x80000000u) hi = 0u;
  return lo | hi;
}
__device__ __forceinline__ uint4 relu_bf8(uint4 v) {
  v.x = relu_bf2(v.x); v.y = relu_bf2(v.y);
  v.z = relu_bf2(v.z); v.w = relu_bf2(v.w);
  return v;
}

// ---------------- W^T bf16 pre-convert: WT[mat][n][k] = bf16(W[mat][k][n]) --
__global__ __launch_bounds__(256)
void conv_wt(const float* __restrict__ W0, const float* __restrict__ W1,
             const float* __restrict__ W2, const float* __restrict__ W3,
             unsigned short* __restrict__ WT) {
  int mat = blockIdx.y;
  const float* W = mat == 0 ? W0 : (mat == 1 ? W1 : (mat == 2 ? W2 : W3));
  int i = blockIdx.x * 256 + threadIdx.x;   // output-linear: coalesced writes
  int n = i >> 8, k = i & 255;
  WT[(size_t)mat * 65536 + i] = f2bf(W[(size_t)k * 256 + n]);
}

// ---------------- bf16 MFMA GEMM: C[M,256] = act(A) @ W (+bias), C bf16 ----
// 256 thr = 4 waves (2x2), tile 128x128, BK=32, mfma_f32_16x16x32_bf16.
template<bool ABF, bool RELU_IN, bool HAS_BIAS>
__global__ __launch_bounds__(256)
void gemm_bf16(const void* __restrict__ Av, const unsigned short* __restrict__ WT,
               const float* __restrict__ bias, unsigned short* __restrict__ C, int M) {
  __shared__ unsigned short As[128 * 32];
  __shared__ unsigned short Bs[128 * 32];
  const int t = threadIdx.x;
  const int lane = t & 63;
  const int w = t >> 6;
  const int wr = (w >> 1) * 64;
  const int wc = (w & 1) * 64;
  const int brow = blockIdx.x * 128;
  const int bcol = blockIdx.y * 128;

  f32x4 acc[4][4];
#pragma unroll
  for (int i = 0; i < 4; i++)
#pragma unroll
    for (int j = 0; j < 4; j++) acc[i][j] = (f32x4)(0.f);

  // staging: thread t covers row ar, 16 k-values at offset ak
  const int ar = t >> 1;
  const int ak = (t & 1) * 16;
  const int grow = brow + ar;
  const bool avalid = grow < M;
  const float* Apf = (const float*)Av + (size_t)(avalid ? grow : 0) * 256 + ak;
  const unsigned short* Aph = (const unsigned short*)Av + (size_t)(avalid ? grow : 0) * 256 + ak;
  const unsigned short* Bp = WT + (size_t)(bcol + ar) * 256 + ak;

  // swizzled LDS byte offsets: addr = row*64 + kbyte, XOR ((row&7)<<4)
  const int aw0 = ((ar * 64 + ak * 2) ^ ((ar & 7) << 4));
  const int aw1 = ((ar * 64 + ak * 2 + 16) ^ ((ar & 7) << 4));

  const int fr = lane & 15, fq = lane >> 4;
  int ard[4], brd[4];
#pragma unroll
  for (int i = 0; i < 4; i++) {
    int rowA = wr + i * 16 + fr;
    ard[i] = ((rowA * 64 + fq * 16) ^ ((rowA & 7) << 4));
    int rowB = wc + i * 16 + fr;
    brd[i] = ((rowB * 64 + fq * 16) ^ ((rowB & 7) << 4));
  }

  for (int k0 = 0; k0 < 256; k0 += 32) {
    if constexpr (ABF) {
      uint4 a0 = make_uint4(0, 0, 0, 0), a1 = make_uint4(0, 0, 0, 0);
      if (avalid) {
        a0 = *(const uint4*)(Aph + k0);
        a1 = *(const uint4*)(Aph + k0 + 8);
      }
      if (RELU_IN) { a0 = relu_bf8(a0); a1 = relu_bf8(a1); }
      *(uint4*)((char*)As + aw0) = a0;
      *(uint4*)((char*)As + aw1) = a1;
    } else {
      union { unsigned short u[8]; uint4 v; } p0, p1;
      float fv[16];
      float4 x0 = avalid ? *(const float4*)(Apf + k0 + 0)  : make_float4(0,0,0,0);
      float4 x1 = avalid ? *(const float4*)(Apf + k0 + 4)  : make_float4(0,0,0,0);
      float4 x2 = avalid ? *(const float4*)(Apf + k0 + 8)  : make_float4(0,0,0,0);
      float4 x3 = avalid ? *(const float4*)(Apf + k0 + 12) : make_float4(0,0,0,0);
      fv[0]=x0.x; fv[1]=x0.y; fv[2]=x0.z; fv[3]=x0.w;
      fv[4]=x1.x; fv[5]=x1.y; fv[6]=x1.z; fv[7]=x1.w;
      fv[8]=x2.x; fv[9]=x2.y; fv[10]=x2.z; fv[11]=x2.w;
      fv[12]=x3.x; fv[13]=x3.y; fv[14]=x3.z; fv[15]=x3.w;
#pragma unroll
      for (int e = 0; e < 8; e++) {
        float a = fv[e], b = fv[8 + e];
        if (RELU_IN) { a = fmaxf(a, 0.f); b = fmaxf(b, 0.f); }
        p0.u[e] = f2bf(a); p1.u[e] = f2bf(b);
      }
      *(uint4*)((char*)As + aw0) = p0.v;
      *(uint4*)((char*)As + aw1) = p1.v;
    }
    // stage B (already bf16, n-major)
    {
      uint4 b0 = *(const uint4*)(Bp + k0);
      uint4 b1 = *(const uint4*)(Bp + k0 + 8);
      *(uint4*)((char*)Bs + aw0) = b0;
      *(uint4*)((char*)Bs + aw1) = b1;
    }
    __syncthreads();
    bf16x8 af[4], bfr[4];
#pragma unroll
    for (int i = 0; i < 4; i++) {
      af[i]  = *(const bf16x8*)((const char*)As + ard[i]);
      bfr[i] = *(const bf16x8*)((const char*)Bs + brd[i]);
    }
#pragma unroll
    for (int i = 0; i < 4; i++)
#pragma unroll
      for (int j = 0; j < 4; j++)
        acc[i][j] = __builtin_amdgcn_mfma_f32_16x16x32_bf16(af[i], bfr[j], acc[i][j], 0, 0, 0);
    __syncthreads();
  }

  // epilogue: D row = (lane>>4)*4 + reg, col = lane&15  [verified layout]
#pragma unroll
  for (int j = 0; j < 4; j++) {
    const int col = bcol + wc + j * 16 + fr;
    const float bj = HAS_BIAS ? bias[col] : 0.f;
#pragma unroll
    for (int i = 0; i < 4; i++) {
#pragma unroll
      for (int r = 0; r < 4; r++) {
        int row = brow + wr + i * 16 + fq * 4 + r;
        if (row < M) C[(size_t)row * 256 + col] = f2bf(acc[i][j][r] + bj);
      }
    }
  }
}

// ---------------- el/er row dots (bf16 feat) --------------------------------
__global__ __launch_bounds__(256)
void rowdots(const unsigned short* __restrict__ feat, const float* __restrict__ al,
             const float* __restrict__ ar, float* __restrict__ el,
             float* __restrict__ er) {
  int row = blockIdx.x * 4 + (threadIdx.x >> 6);
  int lane = threadIdx.x & 63;
  if (row >= NNODES) return;
  ushort4 fv = *(const ushort4*)(feat + (size_t)row * HF + lane * 4);
  float4 a = *(const float4*)(al + lane * 4);
  float4 b = *(const float4*)(ar + lane * 4);
  float f0 = bf2f(fv.x), f1 = bf2f(fv.y), f2 = bf2f(fv.z), f3 = bf2f(fv.w);
  float sl = f0 * a.x + f1 * a.y + f2 * a.z + f3 * a.w;
  float sr = f0 * b.x + f1 * b.y + f2 * b.z + f3 * b.w;
#pragma unroll
  for (int off = 32; off; off >>= 1) {
    sl += __shfl_xor(sl, off);
    sr += __shfl_xor(sr, off);
  }
  if (lane == 0) { el[row] = sl; er[row] = sr; }
}

// ---------------- CSR build -------------------------------------------------
__global__ __launch_bounds__(256)
void hist_dst(const int* __restrict__ dst, int* __restrict__ cnt) {
  int e = blockIdx.x * 256 + threadIdx.x;
  if (e < NEDGES) atomicAdd(&cnt[dst[e]], 1);
}

__global__ __launch_bounds__(256)
void block_sums(const int* __restrict__ cnt, int* __restrict__ bsum) {
  __shared__ int sm[256];
  int t = threadIdx.x;
  int i = blockIdx.x * 256 + t;
  sm[t] = (i < NNODES) ? cnt[i] : 0;
  __syncthreads();
  for (int off = 128; off; off >>= 1) {
    if (t < off) sm[t] += sm[t + off];
    __syncthreads();
  }
  if (t == 0) bsum[blockIdx.x] = sm[0];
}

__global__ __launch_bounds__(256)
void scan_bsums(const int* __restrict__ bsum, int* __restrict__ boff) {
  __shared__ int sm[256];
  int t = threadIdx.x;
  sm[t] = (t < NB) ? bsum[t] : 0;
  __syncthreads();
  for (int off = 1; off < 256; off <<= 1) {
    int v = (t >= off) ? sm[t - off] : 0;
    __syncthreads();
    sm[t] += v;
    __syncthreads();
  }
  if (t < NB) boff[t] = (t == 0) ? 0 : sm[t - 1];
}

__global__ __launch_bounds__(256)
void write_rowptr(const int* __restrict__ cnt, const int* __restrict__ boff,
                  int* __restrict__ rowptr, int* __restrict__ woff) {
  __shared__ int sm[256];
  int t = threadIdx.x;
  int i = blockIdx.x * 256 + t;
  int v = (i < NNODES) ? cnt[i] : 0;
  sm[t] = v;
  __syncthreads();
  for (int off = 1; off < 256; off <<= 1) {
    int x = (t >= off) ? sm[t - off] : 0;
    __syncthreads();
    sm[t] += x;
    __syncthreads();
  }
  int excl = boff[blockIdx.x] + sm[t] - v;
  if (i < NNODES) { rowptr[i] = excl; woff[i] = excl; }
  if (i == NNODES - 1) rowptr[NNODES] = excl + v;
}

__global__ __launch_bounds__(256)
void scatter_csr(const int* __restrict__ src, const int* __restrict__ dst,
                 int* __restrict__ woff, int* __restrict__ col) {
  int e = blockIdx.x * 256 + threadIdx.x;
  if (e >= NEDGES) return;
  int d = dst[e];
  int p = atomicAdd(&woff[d], 1);
  col[p] = src[e];
}

// ---------------- fused GAT edge phase: ONE pass, no segment-max ------------
// softmax shift-invariance: a = exp(x)/sum(exp(x)); x=lrelu(el+er) is O(10),
// exp stays comfortably in fp32 range, so the max-subtraction is unnecessary.
__global__ __launch_bounds__(256)
void gat_csr(const int* __restrict__ rowptr, const int* __restrict__ col,
             const float* __restrict__ el, const float* __restrict__ er,
             const unsigned short* __restrict__ feat, const float* __restrict__ bias,
             unsigned short* __restrict__ h) {
  int d = blockIdx.x * 4 + (threadIdx.x >> 6);
  int lane = threadIdx.x & 63;
  if (d >= NNODES) return;
  const int start = rowptr[d], end = rowptr[d + 1];
  float4 b4 = *(const float4*)(bias + lane * 4);
  unsigned short* hp = h + (size_t)d * HF + lane * 4;
  if (start == end) {
    ushort4 o; o.x = f2bf(b4.x); o.y = f2bf(b4.y); o.z = f2bf(b4.z); o.w = f2bf(b4.w);
    *(ushort4*)hp = o;
    return;
  }
  const float erd = er[d];

  float sm = 0.f;
  float4 acc = make_float4(0.f, 0.f, 0.f, 0.f);
  for (int c0 = start; c0 < end; c0 += 64) {
    int j = c0 + lane;
    float ex = 0.f;
    int s = 0;
    if (j < end) {
      s = col[j];
      float x = el[s] + erd;
      x = x > 0.f ? x : NEG_SLOPE * x;
      ex = __expf(x);
    }
    sm += ex;
    int n = min(64, end - c0);
    for (int q = 0; q < n; q++) {
      float exq = __shfl(ex, q);
      int sq = __shfl(s, q);
      ushort4 fv = *(const ushort4*)(feat + (size_t)sq * HF + lane * 4);
      acc.x = fmaf(exq, bf2f(fv.x), acc.x);
      acc.y = fmaf(exq, bf2f(fv.y), acc.y);
      acc.z = fmaf(exq, bf2f(fv.z), acc.z);
      acc.w = fmaf(exq, bf2f(fv.w), acc.w);
    }
  }
#pragma unroll
  for (int off = 32; off; off >>= 1) sm += __shfl_xor(sm, off);

  const float rcp = 1.f / sm;
  ushort4 o;
  o.x = f2bf(fmaf(acc.x, rcp, b4.x));
  o.y = f2bf(fmaf(acc.y, rcp, b4.y));
  o.z = f2bf(fmaf(acc.z, rcp, b4.z));
  o.w = f2bf(fmaf(acc.w, rcp, b4.w));
  *(ushort4*)hp = o;
}

// ---------------- readout: sigmoid(concat(h1,h2,h3) @ Wro + bro) -----------
__global__ __launch_bounds__(256)
void readout(const unsigned short* __restrict__ h1, const unsigned short* __restrict__ h2,
             const unsigned short* __restrict__ h3, const float* __restrict__ Wro,
             const float* __restrict__ bro, float* __restrict__ out) {
  int row = blockIdx.x * 4 + (threadIdx.x >> 6);
  int lane = threadIdx.x & 63;
  if (row >= NNODES) return;
  float acc[8];
#pragma unroll
  for (int t2 = 0; t2 < 8; t2++) acc[t2] = 0.f;
  const unsigned short* hs[3] = {h1 + (size_t)row * HF, h2 + (size_t)row * HF,
                                 h3 + (size_t)row * HF};
#pragma unroll
  for (int part = 0; part < 3; ++part) {
    const unsigned short* hp = hs[part];
#pragma unroll
    for (int kk = 0; kk < HF; kk += 64) {
      float x = bf2f(hp[kk + lane]);
      const float* w = Wro + (size_t)(part * HF + kk + lane) * 8;
#pragma unroll
      for (int t2 = 0; t2 < 8; t2++) acc[t2] = fmaf(x, w[t2], acc[t2]);
    }
  }
#pragma unroll
  for (int t2 = 0; t2 < 8; t2++)
#pragma unroll
    for (int off = 32; off; off >>= 1) acc[t2] += __shfl_xor(acc[t2], off);
  if (lane == 0) {
#pragma unroll
    for (int t2 = 0; t2 < 8; t2++) {
      float v = acc[t2] + bro[t2];
      out[(size_t)row * 8 + t2] = 1.f / (1.f + expf(-v));
    }
  }
}

extern "C" void kernel_launch(void* const* d_in, const int* in_sizes, int n_in,
                              void* d_out, int out_size, void* d_ws, size_t ws_size,
                              hipStream_t stream) {
  const float* hv   = (const float*)d_in[0];
  const int*   src  = (const int*)d_in[1];
  const int*   dst  = (const int*)d_in[2];
  const float* W_in = (const float*)d_in[3];
  const float* b_in = (const float*)d_in[4];
  const float* W_ro = (const float*)d_in[5];
  const float* b_ro = (const float*)d_in[6];
  const float* fc[3]   = {(const float*)d_in[7],  (const float*)d_in[11], (const float*)d_in[15]};
  const float* al[3]   = {(const float*)d_in[8],  (const float*)d_in[12], (const float*)d_in[16]};
  const float* ar[3]   = {(const float*)d_in[9],  (const float*)d_in[13], (const float*)d_in[17]};
  const float* bias[3] = {(const float*)d_in[10], (const float*)d_in[14], (const float*)d_in[18]};
  float* out = (float*)d_out;

  const size_t NH = (size_t)NNODES * HF;   // 12.8M elems (even)
  unsigned short* h1   = (unsigned short*)d_ws;
  unsigned short* h2   = h1 + NH;
  unsigned short* h3   = h2 + NH;          // also h0 (dead before layer-3 write)
  unsigned short* feat = h3 + NH;
  float* el   = (float*)(feat + NH);
  float* er   = el + NNODES;
  int* rowptr = (int*)(er + NNODES);          // NNODES+1
  int* woff   = rowptr + NNODES + 1;          // NNODES
  int* cnt    = woff + NNODES;                // NNODES
  int* bsum   = cnt + NNODES;                 // 256
  int* boff   = bsum + 256;                   // 256
  int* col    = boff + 256;                   // NEDGES
  unsigned short* WT = (unsigned short*)(col + NEDGES);  // 4*65536 bf16
  unsigned short* h0 = h3;

  const dim3 gemm_grid((NNODES + 127) / 128, 2);
  const int rd_grid = (NNODES + 3) / 4;
  const int ep_grid = (NEDGES + 255) / 256;
  const int gat_grid = (NNODES + 3) / 4;

  // ---- weights -> bf16 W^T (once per launch) ----
  conv_wt<<<dim3(256, 4), 256, 0, stream>>>(W_in, fc[0], fc[1], fc[2], WT);

  // ---- build CSR (dst-sorted adjacency), reused by all 3 layers ----
  hipMemsetAsync(cnt, 0, NNODES * sizeof(int), stream);
  hist_dst<<<ep_grid, 256, 0, stream>>>(dst, cnt);
  block_sums<<<NB, 256, 0, stream>>>(cnt, bsum);
  scan_bsums<<<1, 256, 0, stream>>>(bsum, boff);
  write_rowptr<<<NB, 256, 0, stream>>>(cnt, boff, rowptr, woff);
  scatter_csr<<<ep_grid, 256, 0, stream>>>(src, dst, woff, col);

  // h0 = hv @ W_in + b_in   (fp32 A, converted in staging)
  gemm_bf16<false, false, true><<<gemm_grid, 256, 0, stream>>>(hv, WT, b_in, h0, NNODES);

  unsigned short* hprev = h0;
  unsigned short* houts[3] = {h1, h2, h3};
  for (int l = 0; l < 3; ++l) {
    unsigned short* hl = houts[l];
    // feat = relu(hprev) @ fc_l   (bf16 A)
    gemm_bf16<true, true, false><<<gemm_grid, 256, 0, stream>>>(
        hprev, WT + (size_t)(l + 1) * 65536, nullptr, feat, NNODES);
    rowdots<<<rd_grid, 256, 0, stream>>>(feat, al[l], ar[l], el, er);
    gat_csr<<<gat_grid, 256, 0, stream>>>(rowptr, col, el, er, feat, bias[l], hl);
    hprev = hl;
  }

  readout<<<rd_grid, 256, 0, stream>>>(h1, h2, h3, W_ro, b_ro, out);
}

// Round 5
// 454.345 us; speedup vs baseline: 19.2400x; 1.0794x over previous
//
#include <hip/hip_runtime.h>
#include <hip/hip_bf16.h>
#include <math.h>

#define NNODES 50000
#define NEDGES 800000
#define HF 256
#define NEG_SLOPE 0.2f
#define NB 196        // ceil(NNODES/256)
#define APAD 12288    // 48 pad rows * 256 for async over-read

typedef short bf16x8 __attribute__((ext_vector_type(8)));
typedef float f32x4 __attribute__((ext_vector_type(4)));

__device__ __forceinline__ unsigned short f2bf(float f) {
  unsigned u = __float_as_uint(f);
  unsigned r = u + 0x7FFFu + ((u >> 16) & 1u);
  return (unsigned short)(r >> 16);
}
__device__ __forceinline__ float bf2f(unsigned short u) {
  return __uint_as_float((unsigned)u << 16);
}
__device__ __forceinline__ uint4 pack8(const float* v) {
  uint4 r;
  r.x = (unsigned)f2bf(v[0]) | ((unsigned)f2bf(v[1]) << 16);
  r.y = (unsigned)f2bf(v[2]) | ((unsigned)f2bf(v[3]) << 16);
  r.z = (unsigned)f2bf(v[4]) | ((unsigned)f2bf(v[5]) << 16);
  r.w = (unsigned)f2bf(v[6]) | ((unsigned)f2bf(v[7]) << 16);
  return r;
}

// async 16B global->LDS (wave-uniform LDS base + lane*16)
#define GLOAD_LDS16(gsrc, ldst)                                                \
  __builtin_amdgcn_global_load_lds(                                           \
      (const __attribute__((address_space(1))) unsigned int*)(const void*)(gsrc), \
      (__attribute__((address_space(3))) unsigned int*)(void*)(ldst), 16, 0, 0)

// inverse of slot = (row*4 + kb) ^ (row&7)  [16B granules of a 128x(32 bf16) tile]
__device__ __forceinline__ void slot_decode(int s, int& row, int& kb) {
  row = ((s >> 3) << 1) | (((s >> 2) & 1) ^ ((s >> 4) & 1));
  kb  = ((s & 1) ^ (row & 1)) | ((((s >> 1) & 1) ^ ((s >> 3) & 1)) << 1);
}

// ---------------- hv fp32 -> bf16 (once) ------------------------------------
__global__ __launch_bounds__(256)
void conv_hv(const float* __restrict__ x, unsigned short* __restrict__ o) {
  size_t i = (size_t)(blockIdx.x * 256 + threadIdx.x) * 8;
  float4 a = *(const float4*)(x + i);
  float4 b = *(const float4*)(x + i + 4);
  float v[8] = {a.x, a.y, a.z, a.w, b.x, b.y, b.z, b.w};
  *(uint4*)(o + i) = pack8(v);
}

// ---------------- W^T bf16 pre-convert: WT[mat][n][k] = bf16(W[mat][k][n]) --
__global__ __launch_bounds__(256)
void conv_wt(const float* __restrict__ W0, const float* __restrict__ W1,
             const float* __restrict__ W2, const float* __restrict__ W3,
             unsigned short* __restrict__ WT) {
  int mat = blockIdx.y;
  const float* W = mat == 0 ? W0 : (mat == 1 ? W1 : (mat == 2 ? W2 : W3));
  int i = blockIdx.x * 256 + threadIdx.x;
  int n = i >> 8, k = i & 255;
  WT[(size_t)mat * 65536 + i] = f2bf(W[(size_t)k * 256 + n]);
}

// ---------------- bf16 MFMA GEMM, async-staged -------------------------------
// C[M,256] = A @ W (+bias, +relu). A bf16 [M+pad][256]; W = WT [n][k] bf16.
// 256 thr = 4 waves (2x2), tile 128x128, BK=32, mfma_f32_16x16x32_bf16.
template<bool BIAS_RELU>
__global__ __launch_bounds__(256)
void gemm_bf16(const unsigned short* __restrict__ A, const unsigned short* __restrict__ WT,
               const float* __restrict__ bias, unsigned short* __restrict__ C, int M) {
  __shared__ unsigned short As[128 * 32];
  __shared__ unsigned short Bs[128 * 32];
  const int t = threadIdx.x;
  const int lane = t & 63;
  const int w = t >> 6;
  const int wr = (w >> 1) * 64;
  const int wc = (w & 1) * 64;
  const int brow = blockIdx.x * 128;
  const int bcol = blockIdx.y * 128;

  f32x4 acc[4][4];
#pragma unroll
  for (int i = 0; i < 4; i++)
#pragma unroll
    for (int j = 0; j < 4; j++) acc[i][j] = (f32x4)(0.f);

  // async staging: wave w covers slots [w*128, w*128+128), 2 calls of 64 slots
  const int s0 = w * 128 + lane;
  const int s1 = s0 + 64;
  int rS0, kS0, rS1, kS1;
  slot_decode(s0, rS0, kS0);
  slot_decode(s1, rS1, kS1);
  const unsigned short* a0 = A + (size_t)(brow + rS0) * 256 + kS0 * 8;
  const unsigned short* a1 = A + (size_t)(brow + rS1) * 256 + kS1 * 8;
  const unsigned short* b0 = WT + (size_t)(bcol + rS0) * 256 + kS0 * 8;
  const unsigned short* b1 = WT + (size_t)(bcol + rS1) * 256 + kS1 * 8;
  unsigned short* lA0 = As + (w * 128) * 8;        // wave-uniform bases
  unsigned short* lA1 = As + (w * 128 + 64) * 8;
  unsigned short* lB0 = Bs + (w * 128) * 8;
  unsigned short* lB1 = Bs + (w * 128 + 64) * 8;

  // fragment read offsets (swizzled)
  const int fr = lane & 15, fq = lane >> 4;
  int ard[4], brd[4];
#pragma unroll
  for (int i = 0; i < 4; i++) {
    int rowA = wr + i * 16 + fr;
    ard[i] = ((rowA * 64 + fq * 16) ^ ((rowA & 7) << 4));
    int rowB = wc + i * 16 + fr;
    brd[i] = ((rowB * 64 + fq * 16) ^ ((rowB & 7) << 4));
  }

  for (int k0 = 0; k0 < 256; k0 += 32) {
    GLOAD_LDS16(a0 + k0, lA0);
    GLOAD_LDS16(a1 + k0, lA1);
    GLOAD_LDS16(b0 + k0, lB0);
    GLOAD_LDS16(b1 + k0, lB1);
    __syncthreads();   // drains vmcnt before barrier
    bf16x8 af[4], bfr[4];
#pragma unroll
    for (int i = 0; i < 4; i++) {
      af[i]  = *(const bf16x8*)((const char*)As + ard[i]);
      bfr[i] = *(const bf16x8*)((const char*)Bs + brd[i]);
    }
#pragma unroll
    for (int i = 0; i < 4; i++)
#pragma unroll
      for (int j = 0; j < 4; j++)
        acc[i][j] = __builtin_amdgcn_mfma_f32_16x16x32_bf16(af[i], bfr[j], acc[i][j], 0, 0, 0);
    __syncthreads();
  }

  // epilogue: D row = (lane>>4)*4 + reg, col = lane&15
#pragma unroll
  for (int j = 0; j < 4; j++) {
    const int col = bcol + wc + j * 16 + fr;
    const float bj = BIAS_RELU ? bias[col] : 0.f;
#pragma unroll
    for (int i = 0; i < 4; i++) {
#pragma unroll
      for (int r = 0; r < 4; r++) {
        int row = brow + wr + i * 16 + fq * 4 + r;
        if (row < M) {
          float v = acc[i][j][r];
          if (BIAS_RELU) v = fmaxf(v + bj, 0.f);
          C[(size_t)row * 256 + col] = f2bf(v);
        }
      }
    }
  }
}

// ---------------- el/er row dots (bf16 feat) --------------------------------
__global__ __launch_bounds__(256)
void rowdots(const unsigned short* __restrict__ feat, const float* __restrict__ al,
             const float* __restrict__ ar, float* __restrict__ el,
             float* __restrict__ er) {
  int row = blockIdx.x * 4 + (threadIdx.x >> 6);
  int lane = threadIdx.x & 63;
  if (row >= NNODES) return;
  ushort4 fv = *(const ushort4*)(feat + (size_t)row * HF + lane * 4);
  float4 a = *(const float4*)(al + lane * 4);
  float4 b = *(const float4*)(ar + lane * 4);
  float f0 = bf2f(fv.x), f1 = bf2f(fv.y), f2 = bf2f(fv.z), f3 = bf2f(fv.w);
  float sl = f0 * a.x + f1 * a.y + f2 * a.z + f3 * a.w;
  float sr = f0 * b.x + f1 * b.y + f2 * b.z + f3 * b.w;
#pragma unroll
  for (int off = 32; off; off >>= 1) {
    sl += __shfl_xor(sl, off);
    sr += __shfl_xor(sr, off);
  }
  if (lane == 0) { el[row] = sl; er[row] = sr; }
}

// ---------------- CSR build -------------------------------------------------
__global__ __launch_bounds__(256)
void hist_dst(const int* __restrict__ dst, int* __restrict__ cnt) {
  int e = blockIdx.x * 256 + threadIdx.x;
  if (e < NEDGES) atomicAdd(&cnt[dst[e]], 1);
}

__global__ __launch_bounds__(256)
void block_sums(const int* __restrict__ cnt, int* __restrict__ bsum) {
  __shared__ int sm[256];
  int t = threadIdx.x;
  int i = blockIdx.x * 256 + t;
  sm[t] = (i < NNODES) ? cnt[i] : 0;
  __syncthreads();
  for (int off = 128; off; off >>= 1) {
    if (t < off) sm[t] += sm[t + off];
    __syncthreads();
  }
  if (t == 0) bsum[blockIdx.x] = sm[0];
}

__global__ __launch_bounds__(256)
void scan_bsums(const int* __restrict__ bsum, int* __restrict__ boff) {
  __shared__ int sm[256];
  int t = threadIdx.x;
  sm[t] = (t < NB) ? bsum[t] : 0;
  __syncthreads();
  for (int off = 1; off < 256; off <<= 1) {
    int v = (t >= off) ? sm[t - off] : 0;
    __syncthreads();
    sm[t] += v;
    __syncthreads();
  }
  if (t < NB) boff[t] = (t == 0) ? 0 : sm[t - 1];
}

__global__ __launch_bounds__(256)
void write_rowptr(const int* __restrict__ cnt, const int* __restrict__ boff,
                  int* __restrict__ rowptr, int* __restrict__ woff) {
  __shared__ int sm[256];
  int t = threadIdx.x;
  int i = blockIdx.x * 256 + t;
  int v = (i < NNODES) ? cnt[i] : 0;
  sm[t] = v;
  __syncthreads();
  for (int off = 1; off < 256; off <<= 1) {
    int x = (t >= off) ? sm[t - off] : 0;
    __syncthreads();
    sm[t] += x;
    __syncthreads();
  }
  int excl = boff[blockIdx.x] + sm[t] - v;
  if (i < NNODES) { rowptr[i] = excl; woff[i] = excl; }
  if (i == NNODES - 1) rowptr[NNODES] = excl + v;
}

__global__ __launch_bounds__(256)
void scatter_csr(const int* __restrict__ src, const int* __restrict__ dst,
                 int* __restrict__ woff, int* __restrict__ col) {
  int e = blockIdx.x * 256 + threadIdx.x;
  if (e >= NEDGES) return;
  int d = dst[e];
  int p = atomicAdd(&woff[d], 1);
  col[p] = src[e];
}

// ---------------- fused GAT edge phase: half-wave rows, 4 gathers in flight --
// One wave per dst. Half-wave (32 lanes x 16B) covers a full 512B feat row;
// two edges proceed concurrently, unrolled x2. Writes raw h and relu(h).
__global__ __launch_bounds__(256)
void gat_csr(const int* __restrict__ rowptr, const int* __restrict__ col,
             const float* __restrict__ el, const float* __restrict__ er,
             const unsigned short* __restrict__ feat, const float* __restrict__ bias,
             unsigned short* __restrict__ h, unsigned short* __restrict__ hrelu) {
  int d = blockIdx.x * 4 + (threadIdx.x >> 6);
  int lane = threadIdx.x & 63;
  if (d >= NNODES) return;
  const int start = rowptr[d], end = rowptr[d + 1];
  const int hl8 = (lane & 31) * 8;
  const int half = lane >> 5;
  float bv[8];
  {
    float4 bA = *(const float4*)(bias + hl8);
    float4 bB = *(const float4*)(bias + hl8 + 4);
    bv[0] = bA.x; bv[1] = bA.y; bv[2] = bA.z; bv[3] = bA.w;
    bv[4] = bB.x; bv[5] = bB.y; bv[6] = bB.z; bv[7] = bB.w;
  }
  const size_t obase = (size_t)d * HF + hl8;
  if (start == end) {
    if (lane < 32) {
      float rv[8];
#pragma unroll
      for (int k = 0; k < 8; k++) rv[k] = fmaxf(bv[k], 0.f);
      *(uint4*)(h + obase) = pack8(bv);
      *(uint4*)(hrelu + obase) = pack8(rv);
    }
    return;
  }
  const float erd = er[d];

  float sm = 0.f;
  float ac[8];
#pragma unroll
  for (int k = 0; k < 8; k++) ac[k] = 0.f;

  for (int c0 = start; c0 < end; c0 += 64) {
    int j = c0 + lane;
    float ex = 0.f;
    int s = 0;
    if (j < end) {
      s = col[j];
      float x = el[s] + erd;
      x = x > 0.f ? x : NEG_SLOPE * x;
      ex = __expf(x);
    }
    sm += ex;
    int n = min(64, end - c0);
    for (int q = 0; q < n; q += 4) {
      int qa = q + half, qb = qa + 2;          // invalid lanes carry ex=0, s=0
      float ea = __shfl(ex, qa); int sa = __shfl(s, qa);
      float eb = __shfl(ex, qb); int sb = __shfl(s, qb);
      uint4 fa = *(const uint4*)(feat + (size_t)sa * HF + hl8);
      uint4 fb = *(const uint4*)(feat + (size_t)sb * HF + hl8);
      ac[0] = fmaf(ea, bf2f((unsigned short)(fa.x & 0xffff)), ac[0]);
      ac[1] = fmaf(ea, bf2f((unsigned short)(fa.x >> 16)),    ac[1]);
      ac[2] = fmaf(ea, bf2f((unsigned short)(fa.y & 0xffff)), ac[2]);
      ac[3] = fmaf(ea, bf2f((unsigned short)(fa.y >> 16)),    ac[3]);
      ac[4] = fmaf(ea, bf2f((unsigned short)(fa.z & 0xffff)), ac[4]);
      ac[5] = fmaf(ea, bf2f((unsigned short)(fa.z >> 16)),    ac[5]);
      ac[6] = fmaf(ea, bf2f((unsigned short)(fa.w & 0xffff)), ac[6]);
      ac[7] = fmaf(ea, bf2f((unsigned short)(fa.w >> 16)),    ac[7]);
      ac[0] = fmaf(eb, bf2f((unsigned short)(fb.x & 0xffff)), ac[0]);
      ac[1] = fmaf(eb, bf2f((unsigned short)(fb.x >> 16)),    ac[1]);
      ac[2] = fmaf(eb, bf2f((unsigned short)(fb.y & 0xffff)), ac[2]);
      ac[3] = fmaf(eb, bf2f((unsigned short)(fb.y >> 16)),    ac[3]);
      ac[4] = fmaf(eb, bf2f((unsigned short)(fb.z & 0xffff)), ac[4]);
      ac[5] = fmaf(eb, bf2f((unsigned short)(fb.z >> 16)),    ac[5]);
      ac[6] = fmaf(eb, bf2f((unsigned short)(fb.w & 0xffff)), ac[6]);
      ac[7] = fmaf(eb, bf2f((unsigned short)(fb.w >> 16)),    ac[7]);
    }
  }
#pragma unroll
  for (int off = 32; off; off >>= 1) sm += __shfl_xor(sm, off);
#pragma unroll
  for (int k = 0; k < 8; k++) ac[k] += __shfl_xor(ac[k], 32);

  if (lane < 32) {
    const float rcp = 1.f / sm;
    float ov[8], rv[8];
#pragma unroll
    for (int k = 0; k < 8; k++) {
      ov[k] = fmaf(ac[k], rcp, bv[k]);
      rv[k] = fmaxf(ov[k], 0.f);
    }
    *(uint4*)(h + obase) = pack8(ov);
    *(uint4*)(hrelu + obase) = pack8(rv);
  }
}

// ---------------- readout: sigmoid(concat(h1,h2,h3) @ Wro + bro) -----------
__global__ __launch_bounds__(256)
void readout(const unsigned short* __restrict__ h1, const unsigned short* __restrict__ h2,
             const unsigned short* __restrict__ h3, const float* __restrict__ Wro,
             const float* __restrict__ bro, float* __restrict__ out) {
  int row = blockIdx.x * 4 + (threadIdx.x >> 6);
  int lane = threadIdx.x & 63;
  if (row >= NNODES) return;
  float acc[8];
#pragma unroll
  for (int t2 = 0; t2 < 8; t2++) acc[t2] = 0.f;
  const unsigned short* hs[3] = {h1 + (size_t)row * HF, h2 + (size_t)row * HF,
                                 h3 + (size_t)row * HF};
#pragma unroll
  for (int part = 0; part < 3; ++part) {
    const unsigned short* hp = hs[part];
#pragma unroll
    for (int kk = 0; kk < HF; kk += 64) {
      float x = bf2f(hp[kk + lane]);
      const float* w = Wro + (size_t)(part * HF + kk + lane) * 8;
#pragma unroll
      for (int t2 = 0; t2 < 8; t2++) acc[t2] = fmaf(x, w[t2], acc[t2]);
    }
  }
#pragma unroll
  for (int t2 = 0; t2 < 8; t2++)
#pragma unroll
    for (int off = 32; off; off >>= 1) acc[t2] += __shfl_xor(acc[t2], off);
  if (lane == 0) {
#pragma unroll
    for (int t2 = 0; t2 < 8; t2++) {
      float v = acc[t2] + bro[t2];
      out[(size_t)row * 8 + t2] = 1.f / (1.f + expf(-v));
    }
  }
}

extern "C" void kernel_launch(void* const* d_in, const int* in_sizes, int n_in,
                              void* d_out, int out_size, void* d_ws, size_t ws_size,
                              hipStream_t stream) {
  const float* hv   = (const float*)d_in[0];
  const int*   src  = (const int*)d_in[1];
  const int*   dst  = (const int*)d_in[2];
  const float* W_in = (const float*)d_in[3];
  const float* b_in = (const float*)d_in[4];
  const float* W_ro = (const float*)d_in[5];
  const float* b_ro = (const float*)d_in[6];
  const float* fc[3]   = {(const float*)d_in[7],  (const float*)d_in[11], (const float*)d_in[15]};
  const float* al[3]   = {(const float*)d_in[8],  (const float*)d_in[12], (const float*)d_in[16]};
  const float* ar[3]   = {(const float*)d_in[9],  (const float*)d_in[13], (const float*)d_in[17]};
  const float* bias[3] = {(const float*)d_in[10], (const float*)d_in[14], (const float*)d_in[18]};
  float* out = (float*)d_out;

  const size_t NH = (size_t)NNODES * HF;   // 12.8M elems
  unsigned short* h1    = (unsigned short*)d_ws;
  unsigned short* h2    = h1 + NH;
  unsigned short* h3    = h2 + NH;
  unsigned short* feat  = h3 + NH;
  unsigned short* hrelu = feat + NH;                // +APAD over-read region
  unsigned short* hvbf  = hrelu + NH + APAD;        // +APAD over-read region
  float* el   = (float*)(hvbf + NH + APAD);
  float* er   = el + NNODES;
  int* rowptr = (int*)(er + NNODES);          // NNODES+1
  int* woff   = rowptr + NNODES + 1;          // NNODES
  int* cnt    = woff + NNODES;                // NNODES
  int* bsum   = cnt + NNODES;                 // 256
  int* boff   = bsum + 256;                   // 256
  int* col    = boff + 256;                   // NEDGES
  unsigned short* WT = (unsigned short*)(col + NEDGES);  // 4*65536 bf16

  const dim3 gemm_grid((NNODES + 127) / 128, 2);
  const int rd_grid = (NNODES + 3) / 4;
  const int ep_grid = (NEDGES + 255) / 256;
  const int gat_grid = (NNODES + 3) / 4;

  // ---- one-time converts ----
  conv_hv<<<(int)(NH / 2048), 256, 0, stream>>>(hv, hvbf);
  conv_wt<<<dim3(256, 4), 256, 0, stream>>>(W_in, fc[0], fc[1], fc[2], WT);

  // ---- build CSR (dst-sorted adjacency), reused by all 3 layers ----
  hipMemsetAsync(cnt, 0, NNODES * sizeof(int), stream);
  hist_dst<<<ep_grid, 256, 0, stream>>>(dst, cnt);
  block_sums<<<NB, 256, 0, stream>>>(cnt, bsum);
  scan_bsums<<<1, 256, 0, stream>>>(bsum, boff);
  write_rowptr<<<NB, 256, 0, stream>>>(cnt, boff, rowptr, woff);
  scatter_csr<<<ep_grid, 256, 0, stream>>>(src, dst, woff, col);

  // hrelu = relu(hv @ W_in + b_in)
  gemm_bf16<true><<<gemm_grid, 256, 0, stream>>>(hvbf, WT, b_in, hrelu, NNODES);

  unsigned short* houts[3] = {h1, h2, h3};
  for (int l = 0; l < 3; ++l) {
    unsigned short* hl = houts[l];
    // feat = relu(h_prev) @ fc_l   (A = hrelu, pre-relu'd by producer)
    gemm_bf16<false><<<gemm_grid, 256, 0, stream>>>(
        hrelu, WT + (size_t)(l + 1) * 65536, nullptr, feat, NNODES);
    rowdots<<<rd_grid, 256, 0, stream>>>(feat, al[l], ar[l], el, er);
    gat_csr<<<gat_grid, 256, 0, stream>>>(rowptr, col, el, er, feat, bias[l], hl, hrelu);
  }

  readout<<<rd_grid, 256, 0, stream>>>(h1, h2, h3, W_ro, b_ro, out);
}

// Round 6
// 443.322 us; speedup vs baseline: 19.7184x; 1.0249x over previous
//
#include <hip/hip_runtime.h>
#include <hip/hip_bf16.h>
#include <math.h>

#define NNODES 50000
#define NEDGES 800000
#define HF 256
#define NEG_SLOPE 0.2f
#define NB 196        // ceil(NNODES/256)
#define APAD 12288    // 48 pad rows * 256 for async over-read

typedef short bf16x8 __attribute__((ext_vector_type(8)));
typedef float f32x4 __attribute__((ext_vector_type(4)));
typedef float f32x2 __attribute__((ext_vector_type(2)));

__device__ __forceinline__ unsigned short f2bf(float f) {
  unsigned u = __float_as_uint(f);
  unsigned r = u + 0x7FFFu + ((u >> 16) & 1u);
  return (unsigned short)(r >> 16);
}
__device__ __forceinline__ float bf2f(unsigned short u) {
  return __uint_as_float((unsigned)u << 16);
}
__device__ __forceinline__ f32x2 unpk(unsigned u) {
  f32x2 r;
  r.x = __uint_as_float(u << 16);
  r.y = __uint_as_float(u & 0xffff0000u);
  return r;
}
__device__ __forceinline__ uint4 pack8(const float* v) {
  uint4 r;
  r.x = (unsigned)f2bf(v[0]) | ((unsigned)f2bf(v[1]) << 16);
  r.y = (unsigned)f2bf(v[2]) | ((unsigned)f2bf(v[3]) << 16);
  r.z = (unsigned)f2bf(v[4]) | ((unsigned)f2bf(v[5]) << 16);
  r.w = (unsigned)f2bf(v[6]) | ((unsigned)f2bf(v[7]) << 16);
  return r;
}

// async 16B global->LDS (wave-uniform LDS base + lane*16)
#define GLOAD_LDS16(gsrc, ldst)                                                \
  __builtin_amdgcn_global_load_lds(                                           \
      (const __attribute__((address_space(1))) unsigned int*)(const void*)(gsrc), \
      (__attribute__((address_space(3))) unsigned int*)(void*)(ldst), 16, 0, 0)

// inverse of slot = (row*4 + kb) ^ (row&7)  [16B granules of a 128x(32 bf16) tile]
__device__ __forceinline__ void slot_decode(int s, int& row, int& kb) {
  row = ((s >> 3) << 1) | (((s >> 2) & 1) ^ ((s >> 4) & 1));
  kb  = ((s & 1) ^ (row & 1)) | ((((s >> 1) & 1) ^ ((s >> 3) & 1)) << 1);
}

// ---------------- hv fp32 -> bf16 (once) ------------------------------------
__global__ __launch_bounds__(256)
void conv_hv(const float* __restrict__ x, unsigned short* __restrict__ o) {
  size_t i = (size_t)(blockIdx.x * 256 + threadIdx.x) * 8;
  float4 a = *(const float4*)(x + i);
  float4 b = *(const float4*)(x + i + 4);
  float v[8] = {a.x, a.y, a.z, a.w, b.x, b.y, b.z, b.w};
  *(uint4*)(o + i) = pack8(v);
}

// ---------------- W^T bf16 pre-convert: WT[mat][n][k] = bf16(W[mat][k][n]) --
__global__ __launch_bounds__(256)
void conv_wt(const float* __restrict__ W0, const float* __restrict__ W1,
             const float* __restrict__ W2, const float* __restrict__ W3,
             unsigned short* __restrict__ WT) {
  int mat = blockIdx.y;
  const float* W = mat == 0 ? W0 : (mat == 1 ? W1 : (mat == 2 ? W2 : W3));
  int i = blockIdx.x * 256 + threadIdx.x;
  int n = i >> 8, k = i & 255;
  WT[(size_t)mat * 65536 + i] = f2bf(W[(size_t)k * 256 + n]);
}

// ---------------- bf16 MFMA GEMM, async-staged, double-buffered -------------
// C[M,256] = A @ W (+bias, +relu). A bf16 [M+pad][256]; W = WT [n][k] bf16.
// 256 thr = 4 waves (2x2), tile 128x128, BK=32. T3-min 2-phase schedule:
// STAGE(next) issued before compute(current); ONE __syncthreads per K-step.
template<bool BIAS_RELU>
__global__ __launch_bounds__(256)
void gemm_bf16(const unsigned short* __restrict__ A, const unsigned short* __restrict__ WT,
               const float* __restrict__ bias, unsigned short* __restrict__ C, int M) {
  __shared__ unsigned short As[2][128 * 32];
  __shared__ unsigned short Bs[2][128 * 32];
  const int t = threadIdx.x;
  const int lane = t & 63;
  const int w = t >> 6;
  const int wr = (w >> 1) * 64;
  const int wc = (w & 1) * 64;
  const int brow = blockIdx.x * 128;
  const int bcol = blockIdx.y * 128;

  f32x4 acc[4][4];
#pragma unroll
  for (int i = 0; i < 4; i++)
#pragma unroll
    for (int j = 0; j < 4; j++) acc[i][j] = (f32x4)(0.f);

  // async staging: wave w covers slots [w*128, w*128+128), 2 calls of 64 slots
  const int s0 = w * 128 + lane;
  const int s1 = s0 + 64;
  int rS0, kS0, rS1, kS1;
  slot_decode(s0, rS0, kS0);
  slot_decode(s1, rS1, kS1);
  const unsigned short* a0 = A + (size_t)(brow + rS0) * 256 + kS0 * 8;
  const unsigned short* a1 = A + (size_t)(brow + rS1) * 256 + kS1 * 8;
  const unsigned short* b0 = WT + (size_t)(bcol + rS0) * 256 + kS0 * 8;
  const unsigned short* b1 = WT + (size_t)(bcol + rS1) * 256 + kS1 * 8;
  unsigned short* lA[2] = {&As[0][w * 1024], &As[1][w * 1024]};  // wave-uniform
  unsigned short* lB[2] = {&Bs[0][w * 1024], &Bs[1][w * 1024]};

#define STAGE(buf, kt)                                                         \
  do {                                                                         \
    GLOAD_LDS16(a0 + (kt) * 32, lA[buf]);                                      \
    GLOAD_LDS16(a1 + (kt) * 32, lA[buf] + 512);                                \
    GLOAD_LDS16(b0 + (kt) * 32, lB[buf]);                                      \
    GLOAD_LDS16(b1 + (kt) * 32, lB[buf] + 512);                                \
  } while (0)

  // fragment read offsets (swizzled, byte offsets within one buffer)
  const int fr = lane & 15, fq = lane >> 4;
  int ard[4], brd[4];
#pragma unroll
  for (int i = 0; i < 4; i++) {
    int rowA = wr + i * 16 + fr;
    ard[i] = ((rowA * 64 + fq * 16) ^ ((rowA & 7) << 4));
    int rowB = wc + i * 16 + fr;
    brd[i] = ((rowB * 64 + fq * 16) ^ ((rowB & 7) << 4));
  }

  STAGE(0, 0);
  __syncthreads();   // vmcnt(0) drain + barrier: buf0 ready
  int cur = 0;
#pragma unroll
  for (int kt = 0; kt < 8; kt++) {
    if (kt < 7) STAGE(cur ^ 1, kt + 1);   // issue next tile: hides under MFMA
    bf16x8 af[4], bfr[4];
#pragma unroll
    for (int i = 0; i < 4; i++) {
      af[i]  = *(const bf16x8*)((const char*)As[cur] + ard[i]);
      bfr[i] = *(const bf16x8*)((const char*)Bs[cur] + brd[i]);
    }
#pragma unroll
    for (int i = 0; i < 4; i++)
#pragma unroll
      for (int j = 0; j < 4; j++)
        acc[i][j] = __builtin_amdgcn_mfma_f32_16x16x32_bf16(af[i], bfr[j], acc[i][j], 0, 0, 0);
    if (kt < 7) {
      __syncthreads();  // drains next-tile loads; all waves done reading cur
      cur ^= 1;
    }
  }
#undef STAGE

  // epilogue: D row = (lane>>4)*4 + reg, col = lane&15
#pragma unroll
  for (int j = 0; j < 4; j++) {
    const int col = bcol + wc + j * 16 + fr;
    const float bj = BIAS_RELU ? bias[col] : 0.f;
#pragma unroll
    for (int i = 0; i < 4; i++) {
#pragma unroll
      for (int r = 0; r < 4; r++) {
        int row = brow + wr + i * 16 + fq * 4 + r;
        if (row < M) {
          float v = acc[i][j][r];
          if (BIAS_RELU) v = fmaxf(v + bj, 0.f);
          C[(size_t)row * 256 + col] = f2bf(v);
        }
      }
    }
  }
}

// ---------------- el/er row dots (bf16 feat) --------------------------------
__global__ __launch_bounds__(256)
void rowdots(const unsigned short* __restrict__ feat, const float* __restrict__ al,
             const float* __restrict__ ar, float* __restrict__ el,
             float* __restrict__ er) {
  int row = blockIdx.x * 4 + (threadIdx.x >> 6);
  int lane = threadIdx.x & 63;
  if (row >= NNODES) return;
  ushort4 fv = *(const ushort4*)(feat + (size_t)row * HF + lane * 4);
  float4 a = *(const float4*)(al + lane * 4);
  float4 b = *(const float4*)(ar + lane * 4);
  float f0 = bf2f(fv.x), f1 = bf2f(fv.y), f2 = bf2f(fv.z), f3 = bf2f(fv.w);
  float sl = f0 * a.x + f1 * a.y + f2 * a.z + f3 * a.w;
  float sr = f0 * b.x + f1 * b.y + f2 * b.z + f3 * b.w;
#pragma unroll
  for (int off = 32; off; off >>= 1) {
    sl += __shfl_xor(sl, off);
    sr += __shfl_xor(sr, off);
  }
  if (lane == 0) { el[row] = sl; er[row] = sr; }
}

// ---------------- CSR build -------------------------------------------------
__global__ __launch_bounds__(256)
void hist_dst(const int* __restrict__ dst, int* __restrict__ cnt) {
  int e = blockIdx.x * 256 + threadIdx.x;
  if (e < NEDGES) atomicAdd(&cnt[dst[e]], 1);
}

__global__ __launch_bounds__(256)
void block_sums(const int* __restrict__ cnt, int* __restrict__ bsum) {
  __shared__ int sm[256];
  int t = threadIdx.x;
  int i = blockIdx.x * 256 + t;
  sm[t] = (i < NNODES) ? cnt[i] : 0;
  __syncthreads();
  for (int off = 128; off; off >>= 1) {
    if (t < off) sm[t] += sm[t + off];
    __syncthreads();
  }
  if (t == 0) bsum[blockIdx.x] = sm[0];
}

__global__ __launch_bounds__(256)
void scan_bsums(const int* __restrict__ bsum, int* __restrict__ boff) {
  __shared__ int sm[256];
  int t = threadIdx.x;
  sm[t] = (t < NB) ? bsum[t] : 0;
  __syncthreads();
  for (int off = 1; off < 256; off <<= 1) {
    int v = (t >= off) ? sm[t - off] : 0;
    __syncthreads();
    sm[t] += v;
    __syncthreads();
  }
  if (t < NB) boff[t] = (t == 0) ? 0 : sm[t - 1];
}

__global__ __launch_bounds__(256)
void write_rowptr(const int* __restrict__ cnt, const int* __restrict__ boff,
                  int* __restrict__ rowptr, int* __restrict__ woff) {
  __shared__ int sm[256];
  int t = threadIdx.x;
  int i = blockIdx.x * 256 + t;
  int v = (i < NNODES) ? cnt[i] : 0;
  sm[t] = v;
  __syncthreads();
  for (int off = 1; off < 256; off <<= 1) {
    int x = (t >= off) ? sm[t - off] : 0;
    __syncthreads();
    sm[t] += x;
    __syncthreads();
  }
  int excl = boff[blockIdx.x] + sm[t] - v;
  if (i < NNODES) { rowptr[i] = excl; woff[i] = excl; }
  if (i == NNODES - 1) rowptr[NNODES] = excl + v;
}

__global__ __launch_bounds__(256)
void scatter_csr(const int* __restrict__ src, const int* __restrict__ dst,
                 int* __restrict__ woff, int* __restrict__ col) {
  int e = blockIdx.x * 256 + threadIdx.x;
  if (e >= NEDGES) return;
  int d = dst[e];
  int p = atomicAdd(&woff[d], 1);
  col[p] = src[e];
}

// ---------------- fused GAT edge phase: half-wave rows, 8-deep ILP ----------
// One wave per dst. Half-wave (32 lanes x 16B) covers a full 512B feat row;
// 4 edges per half-wave in flight; packed f32x2 accumulate (v_pk_fma_f32).
template<bool WRITE_RELU>
__global__ __launch_bounds__(256)
void gat_csr(const int* __restrict__ rowptr, const int* __restrict__ col,
             const float* __restrict__ el, const float* __restrict__ er,
             const unsigned short* __restrict__ feat, const float* __restrict__ bias,
             unsigned short* __restrict__ h, unsigned short* __restrict__ hrelu) {
  int d = blockIdx.x * 4 + (threadIdx.x >> 6);
  int lane = threadIdx.x & 63;
  if (d >= NNODES) return;
  const int start = rowptr[d], end = rowptr[d + 1];
  const int hl8 = (lane & 31) * 8;
  const int half = lane >> 5;
  float bv[8];
  {
    float4 bA = *(const float4*)(bias + hl8);
    float4 bB = *(const float4*)(bias + hl8 + 4);
    bv[0] = bA.x; bv[1] = bA.y; bv[2] = bA.z; bv[3] = bA.w;
    bv[4] = bB.x; bv[5] = bB.y; bv[6] = bB.z; bv[7] = bB.w;
  }
  const size_t obase = (size_t)d * HF + hl8;
  if (start == end) {
    if (lane < 32) {
      *(uint4*)(h + obase) = pack8(bv);
      if (WRITE_RELU) {
        float rv[8];
#pragma unroll
        for (int k = 0; k < 8; k++) rv[k] = fmaxf(bv[k], 0.f);
        *(uint4*)(hrelu + obase) = pack8(rv);
      }
    }
    return;
  }
  const float erd = er[d];

  float sm = 0.f;
  f32x2 ac2[4];
#pragma unroll
  for (int k = 0; k < 4; k++) ac2[k] = (f32x2)(0.f);

#define ACC8(f, e)                                                             \
  do {                                                                         \
    f32x2 ev = {(e), (e)};                                                     \
    ac2[0] = unpk((f).x) * ev + ac2[0];                                        \
    ac2[1] = unpk((f).y) * ev + ac2[1];                                        \
    ac2[2] = unpk((f).z) * ev + ac2[2];                                        \
    ac2[3] = unpk((f).w) * ev + ac2[3];                                        \
  } while (0)

  for (int c0 = start; c0 < end; c0 += 64) {
    int j = c0 + lane;
    float ex = 0.f;
    int s = 0;
    if (j < end) {
      s = col[j];
      float x = el[s] + erd;
      x = x > 0.f ? x : NEG_SLOPE * x;
      ex = __expf(x);
    }
    sm += ex;
    int n = min(64, end - c0);
    for (int q = 0; q < n; q += 8) {
      int qb = q + half * 4;                    // invalid lanes carry ex=0,s=0
      float e0 = __shfl(ex, qb + 0); int s0 = __shfl(s, qb + 0);
      float e1 = __shfl(ex, qb + 1); int s1 = __shfl(s, qb + 1);
      float e2 = __shfl(ex, qb + 2); int s2 = __shfl(s, qb + 2);
      float e3 = __shfl(ex, qb + 3); int s3 = __shfl(s, qb + 3);
      uint4 f0 = *(const uint4*)(feat + (size_t)s0 * HF + hl8);
      uint4 f1 = *(const uint4*)(feat + (size_t)s1 * HF + hl8);
      uint4 f2 = *(const uint4*)(feat + (size_t)s2 * HF + hl8);
      uint4 f3 = *(const uint4*)(feat + (size_t)s3 * HF + hl8);
      ACC8(f0, e0);
      ACC8(f1, e1);
      ACC8(f2, e2);
      ACC8(f3, e3);
    }
  }
#undef ACC8
#pragma unroll
  for (int off = 32; off; off >>= 1) sm += __shfl_xor(sm, off);
#pragma unroll
  for (int k = 0; k < 4; k++) {
    ac2[k].x += __shfl_xor(ac2[k].x, 32);
    ac2[k].y += __shfl_xor(ac2[k].y, 32);
  }

  if (lane < 32) {
    const float rcp = 1.f / sm;
    float ov[8];
#pragma unroll
    for (int k = 0; k < 4; k++) {
      ov[2 * k]     = fmaf(ac2[k].x, rcp, bv[2 * k]);
      ov[2 * k + 1] = fmaf(ac2[k].y, rcp, bv[2 * k + 1]);
    }
    *(uint4*)(h + obase) = pack8(ov);
    if (WRITE_RELU) {
      float rv[8];
#pragma unroll
      for (int k = 0; k < 8; k++) rv[k] = fmaxf(ov[k], 0.f);
      *(uint4*)(hrelu + obase) = pack8(rv);
    }
  }
}

// ---------------- readout: sigmoid(concat(h1,h2,h3) @ Wro + bro) -----------
__global__ __launch_bounds__(256)
void readout(const unsigned short* __restrict__ h1, const unsigned short* __restrict__ h2,
             const unsigned short* __restrict__ h3, const float* __restrict__ Wro,
             const float* __restrict__ bro, float* __restrict__ out) {
  int row = blockIdx.x * 4 + (threadIdx.x >> 6);
  int lane = threadIdx.x & 63;
  if (row >= NNODES) return;
  float acc[8];
#pragma unroll
  for (int t2 = 0; t2 < 8; t2++) acc[t2] = 0.f;
  const unsigned short* hs[3] = {h1 + (size_t)row * HF, h2 + (size_t)row * HF,
                                 h3 + (size_t)row * HF};
#pragma unroll
  for (int part = 0; part < 3; ++part) {
    const unsigned short* hp = hs[part];
#pragma unroll
    for (int kk = 0; kk < HF; kk += 64) {
      float x = bf2f(hp[kk + lane]);
      const float* w = Wro + (size_t)(part * HF + kk + lane) * 8;
#pragma unroll
      for (int t2 = 0; t2 < 8; t2++) acc[t2] = fmaf(x, w[t2], acc[t2]);
    }
  }
#pragma unroll
  for (int t2 = 0; t2 < 8; t2++)
#pragma unroll
    for (int off = 32; off; off >>= 1) acc[t2] += __shfl_xor(acc[t2], off);
  if (lane == 0) {
#pragma unroll
    for (int t2 = 0; t2 < 8; t2++) {
      float v = acc[t2] + bro[t2];
      out[(size_t)row * 8 + t2] = 1.f / (1.f + expf(-v));
    }
  }
}

extern "C" void kernel_launch(void* const* d_in, const int* in_sizes, int n_in,
                              void* d_out, int out_size, void* d_ws, size_t ws_size,
                              hipStream_t stream) {
  const float* hv   = (const float*)d_in[0];
  const int*   src  = (const int*)d_in[1];
  const int*   dst  = (const int*)d_in[2];
  const float* W_in = (const float*)d_in[3];
  const float* b_in = (const float*)d_in[4];
  const float* W_ro = (const float*)d_in[5];
  const float* b_ro = (const float*)d_in[6];
  const float* fc[3]   = {(const float*)d_in[7],  (const float*)d_in[11], (const float*)d_in[15]};
  const float* al[3]   = {(const float*)d_in[8],  (const float*)d_in[12], (const float*)d_in[16]};
  const float* ar[3]   = {(const float*)d_in[9],  (const float*)d_in[13], (const float*)d_in[17]};
  const float* bias[3] = {(const float*)d_in[10], (const float*)d_in[14], (const float*)d_in[18]};
  float* out = (float*)d_out;

  const size_t NH = (size_t)NNODES * HF;   // 12.8M elems
  unsigned short* h1    = (unsigned short*)d_ws;
  unsigned short* h2    = h1 + NH;
  unsigned short* h3    = h2 + NH;
  unsigned short* feat  = h3 + NH;
  unsigned short* hrelu = feat + NH;                // +APAD over-read region
  unsigned short* hvbf  = hrelu + NH + APAD;        // +APAD over-read region
  float* el   = (float*)(hvbf + NH + APAD);
  float* er   = el + NNODES;
  int* rowptr = (int*)(er + NNODES);          // NNODES+1
  int* woff   = rowptr + NNODES + 1;          // NNODES
  int* cnt    = woff + NNODES;                // NNODES
  int* bsum   = cnt + NNODES;                 // 256
  int* boff   = bsum + 256;                   // 256
  int* col    = boff + 256;                   // NEDGES
  unsigned short* WT = (unsigned short*)(col + NEDGES);  // 4*65536 bf16

  const dim3 gemm_grid((NNODES + 127) / 128, 2);
  const int rd_grid = (NNODES + 3) / 4;
  const int ep_grid = (NEDGES + 255) / 256;
  const int gat_grid = (NNODES + 3) / 4;

  // ---- one-time converts ----
  conv_hv<<<(int)(NH / 2048), 256, 0, stream>>>(hv, hvbf);
  conv_wt<<<dim3(256, 4), 256, 0, stream>>>(W_in, fc[0], fc[1], fc[2], WT);

  // ---- build CSR (dst-sorted adjacency), reused by all 3 layers ----
  hipMemsetAsync(cnt, 0, NNODES * sizeof(int), stream);
  hist_dst<<<ep_grid, 256, 0, stream>>>(dst, cnt);
  block_sums<<<NB, 256, 0, stream>>>(cnt, bsum);
  scan_bsums<<<1, 256, 0, stream>>>(bsum, boff);
  write_rowptr<<<NB, 256, 0, stream>>>(cnt, boff, rowptr, woff);
  scatter_csr<<<ep_grid, 256, 0, stream>>>(src, dst, woff, col);

  // hrelu = relu(hv @ W_in + b_in)
  gemm_bf16<true><<<gemm_grid, 256, 0, stream>>>(hvbf, WT, b_in, hrelu, NNODES);

  unsigned short* houts[3] = {h1, h2, h3};
  for (int l = 0; l < 3; ++l) {
    unsigned short* hl = houts[l];
    // feat = relu(h_prev) @ fc_l   (A = hrelu, pre-relu'd by producer)
    gemm_bf16<false><<<gemm_grid, 256, 0, stream>>>(
        hrelu, WT + (size_t)(l + 1) * 65536, nullptr, feat, NNODES);
    rowdots<<<rd_grid, 256, 0, stream>>>(feat, al[l], ar[l], el, er);
    if (l < 2)
      gat_csr<true><<<gat_grid, 256, 0, stream>>>(rowptr, col, el, er, feat, bias[l], hl, hrelu);
    else
      gat_csr<false><<<gat_grid, 256, 0, stream>>>(rowptr, col, el, er, feat, bias[l], hl, hrelu);
  }

  readout<<<rd_grid, 256, 0, stream>>>(h1, h2, h3, W_ro, b_ro, out);
}

// Round 7
// 441.298 us; speedup vs baseline: 19.8088x; 1.0046x over previous
//
#include <hip/hip_runtime.h>
#include <hip/hip_bf16.h>
#include <math.h>

#define NNODES 50000
#define NEDGES 800000
#define HF 256
#define NEG_SLOPE 0.2f
#define NB 196        // ceil(NNODES/256)
#define APAD 12288    // 48 pad rows * 256 for async over-read

typedef short bf16x8 __attribute__((ext_vector_type(8)));
typedef float f32x4 __attribute__((ext_vector_type(4)));
typedef float f32x2 __attribute__((ext_vector_type(2)));

__device__ __forceinline__ unsigned short f2bf(float f) {
  unsigned u = __float_as_uint(f);
  unsigned r = u + 0x7FFFu + ((u >> 16) & 1u);
  return (unsigned short)(r >> 16);
}
__device__ __forceinline__ float bf2f(unsigned short u) {
  return __uint_as_float((unsigned)u << 16);
}
__device__ __forceinline__ f32x2 unpk(unsigned u) {
  f32x2 r;
  r.x = __uint_as_float(u << 16);
  r.y = __uint_as_float(u & 0xffff0000u);
  return r;
}
__device__ __forceinline__ uint4 pack8(const float* v) {
  uint4 r;
  r.x = (unsigned)f2bf(v[0]) | ((unsigned)f2bf(v[1]) << 16);
  r.y = (unsigned)f2bf(v[2]) | ((unsigned)f2bf(v[3]) << 16);
  r.z = (unsigned)f2bf(v[4]) | ((unsigned)f2bf(v[5]) << 16);
  r.w = (unsigned)f2bf(v[6]) | ((unsigned)f2bf(v[7]) << 16);
  return r;
}

// async 16B global->LDS (wave-uniform LDS base + lane*16)
#define GLOAD_LDS16(gsrc, ldst)                                                \
  __builtin_amdgcn_global_load_lds(                                           \
      (const __attribute__((address_space(1))) unsigned int*)(const void*)(gsrc), \
      (__attribute__((address_space(3))) unsigned int*)(void*)(ldst), 16, 0, 0)

// inverse of slot = (row*4 + kb) ^ (row&7)  [16B granules of a Rx(32 bf16) tile]
__device__ __forceinline__ void slot_decode(int s, int& row, int& kb) {
  row = ((s >> 3) << 1) | (((s >> 2) & 1) ^ ((s >> 4) & 1));
  kb  = ((s & 1) ^ (row & 1)) | ((((s >> 1) & 1) ^ ((s >> 3) & 1)) << 1);
}

// ---------------- hv fp32 -> bf16 (once) ------------------------------------
__global__ __launch_bounds__(256)
void conv_hv(const float* __restrict__ x, unsigned short* __restrict__ o) {
  size_t i = (size_t)(blockIdx.x * 256 + threadIdx.x) * 8;
  float4 a = *(const float4*)(x + i);
  float4 b = *(const float4*)(x + i + 4);
  float v[8] = {a.x, a.y, a.z, a.w, b.x, b.y, b.z, b.w};
  *(uint4*)(o + i) = pack8(v);
}

// ---------------- W^T bf16 pre-convert: WT[mat][n][k] = bf16(W[mat][k][n]) --
__global__ __launch_bounds__(256)
void conv_wt(const float* __restrict__ W0, const float* __restrict__ W1,
             const float* __restrict__ W2, const float* __restrict__ W3,
             unsigned short* __restrict__ WT) {
  int mat = blockIdx.y;
  const float* W = mat == 0 ? W0 : (mat == 1 ? W1 : (mat == 2 ? W2 : W3));
  int i = blockIdx.x * 256 + threadIdx.x;
  int n = i >> 8, k = i & 255;
  WT[(size_t)mat * 65536 + i] = f2bf(W[(size_t)k * 256 + n]);
}

// ---------------- bf16 MFMA GEMM, BM=128 BN=256 BK=32, async dbuf -----------
// C[M,256] = A @ W (+bias+relu | +fused el/er dots). 512 thr = 8 waves (4x2),
// each wave 32 rows x 128 cols, acc[2][8]. One column-block: A fetched once.
template<bool BIAS_RELU, bool DOTS>
__global__ __launch_bounds__(512)
void gemm_bf16(const unsigned short* __restrict__ A, const unsigned short* __restrict__ WT,
               const float* __restrict__ bias,
               const float* __restrict__ al, const float* __restrict__ ar,
               unsigned short* __restrict__ C,
               float* __restrict__ el, float* __restrict__ er, int M) {
  __shared__ unsigned short As[2][128 * 32];   // 16 KB
  __shared__ unsigned short Bs[2][256 * 32];   // 32 KB
  const int t = threadIdx.x;
  const int lane = t & 63;
  const int w = t >> 6;               // 0..7
  const int wr = (w >> 1) * 32;       // row band
  const int wc = (w & 1) * 128;       // col half
  const int brow = blockIdx.x * 128;

  f32x4 acc[2][8];
#pragma unroll
  for (int i = 0; i < 2; i++)
#pragma unroll
    for (int j = 0; j < 8; j++) acc[i][j] = (f32x4)(0.f);

  // staging slots: A 512 granules (1/wave-lane), B 1024 (2/wave-lane)
  int rA, kA, rB0, kB0, rB1, kB1;
  slot_decode(w * 64 + lane, rA, kA);
  slot_decode(w * 128 + lane, rB0, kB0);
  slot_decode(w * 128 + 64 + lane, rB1, kB1);
  const unsigned short* aP  = A + (size_t)(brow + rA) * 256 + kA * 8;
  const unsigned short* bP0 = WT + (size_t)rB0 * 256 + kB0 * 8;
  const unsigned short* bP1 = WT + (size_t)rB1 * 256 + kB1 * 8;
  unsigned short* lA[2] = {&As[0][w * 512], &As[1][w * 512]};     // wave-uniform
  unsigned short* lB[2] = {&Bs[0][w * 1024], &Bs[1][w * 1024]};

#define STAGE(buf, kt)                                                         \
  do {                                                                         \
    GLOAD_LDS16(aP + (kt) * 32, lA[buf]);                                      \
    GLOAD_LDS16(bP0 + (kt) * 32, lB[buf]);                                     \
    GLOAD_LDS16(bP1 + (kt) * 32, lB[buf] + 512);                               \
  } while (0)

  // fragment read offsets (swizzled byte offsets within one buffer)
  const int fr = lane & 15, fq = lane >> 4;
  int ard[2], brd[8];
#pragma unroll
  for (int i = 0; i < 2; i++) {
    int rowA = wr + i * 16 + fr;
    ard[i] = ((rowA * 64 + fq * 16) ^ ((rowA & 7) << 4));
  }
#pragma unroll
  for (int j = 0; j < 8; j++) {
    int rowB = wc + j * 16 + fr;
    brd[j] = ((rowB * 64 + fq * 16) ^ ((rowB & 7) << 4));
  }

  STAGE(0, 0);
  __syncthreads();   // vmcnt(0) drain + barrier: buf0 ready
  int cur = 0;
#pragma unroll
  for (int kt = 0; kt < 8; kt++) {
    if (kt < 7) STAGE(cur ^ 1, kt + 1);   // next tile hides under MFMA
    bf16x8 af[2], bfr[8];
#pragma unroll
    for (int i = 0; i < 2; i++)
      af[i] = *(const bf16x8*)((const char*)As[cur] + ard[i]);
#pragma unroll
    for (int j = 0; j < 8; j++)
      bfr[j] = *(const bf16x8*)((const char*)Bs[cur] + brd[j]);
#pragma unroll
    for (int i = 0; i < 2; i++)
#pragma unroll
      for (int j = 0; j < 8; j++)
        acc[i][j] = __builtin_amdgcn_mfma_f32_16x16x32_bf16(af[i], bfr[j], acc[i][j], 0, 0, 0);
    if (kt < 7) {
      __syncthreads();
      cur ^= 1;
    }
  }
#undef STAGE

  // epilogue: D row = (lane>>4)*4 + reg, col = lane&15  [verified layout]
#pragma unroll
  for (int j = 0; j < 8; j++) {
    const int col = wc + j * 16 + fr;
    const float bj = BIAS_RELU ? bias[col] : 0.f;
#pragma unroll
    for (int i = 0; i < 2; i++) {
#pragma unroll
      for (int r = 0; r < 4; r++) {
        int row = brow + wr + i * 16 + fq * 4 + r;
        if (row < M) {
          float v = acc[i][j][r];
          if (BIAS_RELU) v = fmaxf(v + bj, 0.f);
          C[(size_t)row * 256 + col] = f2bf(v);
        }
      }
    }
  }

  if constexpr (DOTS) {
    // el/er partial dots from fp32 acc: reduce over this wave's 128 cols,
    // then across the 16 fr-lanes, then atomicAdd (2 col-waves per row).
    float alv[8], arv[8];
#pragma unroll
    for (int j = 0; j < 8; j++) {
      int col = wc + j * 16 + fr;
      alv[j] = al[col];
      arv[j] = ar[col];
    }
    float pel[8], per_[8];
#pragma unroll
    for (int i = 0; i < 2; i++)
#pragma unroll
      for (int r = 0; r < 4; r++) {
        float se = 0.f, sr = 0.f;
#pragma unroll
        for (int j = 0; j < 8; j++) {
          se = fmaf(acc[i][j][r], alv[j], se);
          sr = fmaf(acc[i][j][r], arv[j], sr);
        }
        pel[i * 4 + r] = se;
        per_[i * 4 + r] = sr;
      }
#pragma unroll
    for (int off = 1; off < 16; off <<= 1)
#pragma unroll
      for (int k = 0; k < 8; k++) {
        pel[k] += __shfl_xor(pel[k], off);
        per_[k] += __shfl_xor(per_[k], off);
      }
    if (fr == 0) {
#pragma unroll
      for (int i = 0; i < 2; i++)
#pragma unroll
        for (int r = 0; r < 4; r++) {
          int row = brow + wr + i * 16 + fq * 4 + r;
          if (row < M) {
            unsafeAtomicAdd(el + row, pel[i * 4 + r]);
            unsafeAtomicAdd(er + row, per_[i * 4 + r]);
          }
        }
    }
  }
}

// ---------------- CSR build -------------------------------------------------
__global__ __launch_bounds__(256)
void hist_dst(const int* __restrict__ dst, int* __restrict__ cnt) {
  int e = blockIdx.x * 256 + threadIdx.x;
  if (e < NEDGES) atomicAdd(&cnt[dst[e]], 1);
}

__global__ __launch_bounds__(256)
void block_sums(const int* __restrict__ cnt, int* __restrict__ bsum) {
  __shared__ int sm[256];
  int t = threadIdx.x;
  int i = blockIdx.x * 256 + t;
  sm[t] = (i < NNODES) ? cnt[i] : 0;
  __syncthreads();
  for (int off = 128; off; off >>= 1) {
    if (t < off) sm[t] += sm[t + off];
    __syncthreads();
  }
  if (t == 0) bsum[blockIdx.x] = sm[0];
}

__global__ __launch_bounds__(256)
void scan_bsums(const int* __restrict__ bsum, int* __restrict__ boff) {
  __shared__ int sm[256];
  int t = threadIdx.x;
  sm[t] = (t < NB) ? bsum[t] : 0;
  __syncthreads();
  for (int off = 1; off < 256; off <<= 1) {
    int v = (t >= off) ? sm[t - off] : 0;
    __syncthreads();
    sm[t] += v;
    __syncthreads();
  }
  if (t < NB) boff[t] = (t == 0) ? 0 : sm[t - 1];
}

__global__ __launch_bounds__(256)
void write_rowptr(const int* __restrict__ cnt, const int* __restrict__ boff,
                  int* __restrict__ rowptr, int* __restrict__ woff) {
  __shared__ int sm[256];
  int t = threadIdx.x;
  int i = blockIdx.x * 256 + t;
  int v = (i < NNODES) ? cnt[i] : 0;
  sm[t] = v;
  __syncthreads();
  for (int off = 1; off < 256; off <<= 1) {
    int x = (t >= off) ? sm[t - off] : 0;
    __syncthreads();
    sm[t] += x;
    __syncthreads();
  }
  int excl = boff[blockIdx.x] + sm[t] - v;
  if (i < NNODES) { rowptr[i] = excl; woff[i] = excl; }
  if (i == NNODES - 1) rowptr[NNODES] = excl + v;
}

__global__ __launch_bounds__(256)
void scatter_csr(const int* __restrict__ src, const int* __restrict__ dst,
                 int* __restrict__ woff, int* __restrict__ col) {
  int e = blockIdx.x * 256 + threadIdx.x;
  if (e >= NEDGES) return;
  int d = dst[e];
  int p = atomicAdd(&woff[d], 1);
  col[p] = src[e];
}

// ---------------- fused GAT edge phase: half-wave rows, 8-deep ILP ----------
template<bool WRITE_RELU>
__global__ __launch_bounds__(256)
void gat_csr(const int* __restrict__ rowptr, const int* __restrict__ col,
             const float* __restrict__ el, const float* __restrict__ er,
             const unsigned short* __restrict__ feat, const float* __restrict__ bias,
             unsigned short* __restrict__ h, unsigned short* __restrict__ hrelu) {
  int d = blockIdx.x * 4 + (threadIdx.x >> 6);
  int lane = threadIdx.x & 63;
  if (d >= NNODES) return;
  const int start = rowptr[d], end = rowptr[d + 1];
  const int hl8 = (lane & 31) * 8;
  const int half = lane >> 5;
  float bv[8];
  {
    float4 bA = *(const float4*)(bias + hl8);
    float4 bB = *(const float4*)(bias + hl8 + 4);
    bv[0] = bA.x; bv[1] = bA.y; bv[2] = bA.z; bv[3] = bA.w;
    bv[4] = bB.x; bv[5] = bB.y; bv[6] = bB.z; bv[7] = bB.w;
  }
  const size_t obase = (size_t)d * HF + hl8;
  if (start == end) {
    if (lane < 32) {
      *(uint4*)(h + obase) = pack8(bv);
      if (WRITE_RELU) {
        float rv[8];
#pragma unroll
        for (int k = 0; k < 8; k++) rv[k] = fmaxf(bv[k], 0.f);
        *(uint4*)(hrelu + obase) = pack8(rv);
      }
    }
    return;
  }
  const float erd = er[d];

  float sm = 0.f;
  f32x2 ac2[4];
#pragma unroll
  for (int k = 0; k < 4; k++) ac2[k] = (f32x2)(0.f);

#define ACC8(f, e)                                                             \
  do {                                                                         \
    f32x2 ev = {(e), (e)};                                                     \
    ac2[0] = unpk((f).x) * ev + ac2[0];                                        \
    ac2[1] = unpk((f).y) * ev + ac2[1];                                        \
    ac2[2] = unpk((f).z) * ev + ac2[2];                                        \
    ac2[3] = unpk((f).w) * ev + ac2[3];                                        \
  } while (0)

  for (int c0 = start; c0 < end; c0 += 64) {
    int j = c0 + lane;
    float ex = 0.f;
    int s = 0;
    if (j < end) {
      s = col[j];
      float x = el[s] + erd;
      x = x > 0.f ? x : NEG_SLOPE * x;
      ex = __expf(x);
    }
    sm += ex;
    int n = min(64, end - c0);
    for (int q = 0; q < n; q += 8) {
      int qb = q + half * 4;                    // invalid lanes carry ex=0,s=0
      float e0 = __shfl(ex, qb + 0); int s0 = __shfl(s, qb + 0);
      float e1 = __shfl(ex, qb + 1); int s1 = __shfl(s, qb + 1);
      float e2 = __shfl(ex, qb + 2); int s2 = __shfl(s, qb + 2);
      float e3 = __shfl(ex, qb + 3); int s3 = __shfl(s, qb + 3);
      uint4 f0 = *(const uint4*)(feat + (size_t)s0 * HF + hl8);
      uint4 f1 = *(const uint4*)(feat + (size_t)s1 * HF + hl8);
      uint4 f2 = *(const uint4*)(feat + (size_t)s2 * HF + hl8);
      uint4 f3 = *(const uint4*)(feat + (size_t)s3 * HF + hl8);
      ACC8(f0, e0);
      ACC8(f1, e1);
      ACC8(f2, e2);
      ACC8(f3, e3);
    }
  }
#undef ACC8
#pragma unroll
  for (int off = 32; off; off >>= 1) sm += __shfl_xor(sm, off);
#pragma unroll
  for (int k = 0; k < 4; k++) {
    ac2[k].x += __shfl_xor(ac2[k].x, 32);
    ac2[k].y += __shfl_xor(ac2[k].y, 32);
  }

  if (lane < 32) {
    const float rcp = 1.f / sm;
    float ov[8];
#pragma unroll
    for (int k = 0; k < 4; k++) {
      ov[2 * k]     = fmaf(ac2[k].x, rcp, bv[2 * k]);
      ov[2 * k + 1] = fmaf(ac2[k].y, rcp, bv[2 * k + 1]);
    }
    *(uint4*)(h + obase) = pack8(ov);
    if (WRITE_RELU) {
      float rv[8];
#pragma unroll
      for (int k = 0; k < 8; k++) rv[k] = fmaxf(ov[k], 0.f);
      *(uint4*)(hrelu + obase) = pack8(rv);
    }
  }
}

// ---------------- readout: sigmoid(concat(h1,h2,h3) @ Wro + bro) -----------
__global__ __launch_bounds__(256)
void readout(const unsigned short* __restrict__ h1, const unsigned short* __restrict__ h2,
             const unsigned short* __restrict__ h3, const float* __restrict__ Wro,
             const float* __restrict__ bro, float* __restrict__ out) {
  int row = blockIdx.x * 4 + (threadIdx.x >> 6);
  int lane = threadIdx.x & 63;
  if (row >= NNODES) return;
  float acc[8];
#pragma unroll
  for (int t2 = 0; t2 < 8; t2++) acc[t2] = 0.f;
  const unsigned short* hs[3] = {h1 + (size_t)row * HF, h2 + (size_t)row * HF,
                                 h3 + (size_t)row * HF};
#pragma unroll
  for (int part = 0; part < 3; ++part) {
    const unsigned short* hp = hs[part];
#pragma unroll
    for (int kk = 0; kk < HF; kk += 64) {
      float x = bf2f(hp[kk + lane]);
      const float* w = Wro + (size_t)(part * HF + kk + lane) * 8;
#pragma unroll
      for (int t2 = 0; t2 < 8; t2++) acc[t2] = fmaf(x, w[t2], acc[t2]);
    }
  }
#pragma unroll
  for (int t2 = 0; t2 < 8; t2++)
#pragma unroll
    for (int off = 32; off; off >>= 1) acc[t2] += __shfl_xor(acc[t2], off);
  if (lane == 0) {
#pragma unroll
    for (int t2 = 0; t2 < 8; t2++) {
      float v = acc[t2] + bro[t2];
      out[(size_t)row * 8 + t2] = 1.f / (1.f + expf(-v));
    }
  }
}

extern "C" void kernel_launch(void* const* d_in, const int* in_sizes, int n_in,
                              void* d_out, int out_size, void* d_ws, size_t ws_size,
                              hipStream_t stream) {
  const float* hv   = (const float*)d_in[0];
  const int*   src  = (const int*)d_in[1];
  const int*   dst  = (const int*)d_in[2];
  const float* W_in = (const float*)d_in[3];
  const float* b_in = (const float*)d_in[4];
  const float* W_ro = (const float*)d_in[5];
  const float* b_ro = (const float*)d_in[6];
  const float* fc[3]   = {(const float*)d_in[7],  (const float*)d_in[11], (const float*)d_in[15]};
  const float* al[3]   = {(const float*)d_in[8],  (const float*)d_in[12], (const float*)d_in[16]};
  const float* ar[3]   = {(const float*)d_in[9],  (const float*)d_in[13], (const float*)d_in[17]};
  const float* bias[3] = {(const float*)d_in[10], (const float*)d_in[14], (const float*)d_in[18]};
  float* out = (float*)d_out;

  const size_t NH = (size_t)NNODES * HF;   // 12.8M elems
  unsigned short* h1    = (unsigned short*)d_ws;
  unsigned short* h2    = h1 + NH;
  unsigned short* h3    = h2 + NH;
  unsigned short* feat  = h3 + NH;
  unsigned short* hrelu = feat + NH;                // +APAD over-read region
  unsigned short* hvbf  = hrelu + NH + APAD;        // +APAD over-read region
  float* el   = (float*)(hvbf + NH + APAD);
  float* er   = el + NNODES;
  int* rowptr = (int*)(er + NNODES);          // NNODES+1
  int* woff   = rowptr + NNODES + 1;          // NNODES
  int* cnt    = woff + NNODES;                // NNODES
  int* bsum   = cnt + NNODES;                 // 256
  int* boff   = bsum + 256;                   // 256
  int* col    = boff + 256;                   // NEDGES
  unsigned short* WT = (unsigned short*)(col + NEDGES);  // 4*65536 bf16

  const int gemm_grid = (NNODES + 127) / 128;   // 391, single column block
  const int rd_grid = (NNODES + 3) / 4;
  const int ep_grid = (NEDGES + 255) / 256;
  const int gat_grid = (NNODES + 3) / 4;

  // ---- one-time converts ----
  conv_hv<<<(int)(NH / 2048), 256, 0, stream>>>(hv, hvbf);
  conv_wt<<<dim3(256, 4), 256, 0, stream>>>(W_in, fc[0], fc[1], fc[2], WT);

  // ---- build CSR (dst-sorted adjacency), reused by all 3 layers ----
  hipMemsetAsync(cnt, 0, NNODES * sizeof(int), stream);
  hist_dst<<<ep_grid, 256, 0, stream>>>(dst, cnt);
  block_sums<<<NB, 256, 0, stream>>>(cnt, bsum);
  scan_bsums<<<1, 256, 0, stream>>>(bsum, boff);
  write_rowptr<<<NB, 256, 0, stream>>>(cnt, boff, rowptr, woff);
  scatter_csr<<<ep_grid, 256, 0, stream>>>(src, dst, woff, col);

  // hrelu = relu(hv @ W_in + b_in)
  gemm_bf16<true, false><<<gemm_grid, 512, 0, stream>>>(
      hvbf, WT, b_in, nullptr, nullptr, hrelu, nullptr, nullptr, NNODES);

  unsigned short* houts[3] = {h1, h2, h3};
  for (int l = 0; l < 3; ++l) {
    unsigned short* hl = houts[l];
    // feat = relu(h_prev) @ fc_l, with fused el/er dots (atomic accumulate)
    hipMemsetAsync(el, 0, 2 * NNODES * sizeof(float), stream);
    gemm_bf16<false, true><<<gemm_grid, 512, 0, stream>>>(
        hrelu, WT + (size_t)(l + 1) * 65536, nullptr, al[l], ar[l], feat, el, er, NNODES);
    if (l < 2)
      gat_csr<true><<<gat_grid, 256, 0, stream>>>(rowptr, col, el, er, feat, bias[l], hl, hrelu);
    else
      gat_csr<false><<<gat_grid, 256, 0, stream>>>(rowptr, col, el, er, feat, bias[l], hl, hrelu);
  }

  readout<<<rd_grid, 256, 0, stream>>>(h1, h2, h3, W_ro, b_ro, out);
}